// Round 1
// baseline (1061.674 us; speedup 1.0000x reference)
//
#include <hip/hip_runtime.h>
#include <math.h>

// Problem constants
constexpr int kBS = 32, kM = 128, kNMAT = kBS * kM;         // 4096 (b,m) pairs
constexpr int kDIN = 64, kDOUT = 32, kMSZ = kDOUT * kDOUT;  // 1024 floats per 32x32
constexpr int kNSweep = 8;                                  // Jacobi sweeps (fixed, deterministic)

// ws layout (floats):
//   P/log : [3][4096][1024]  (Q=0,K=1,V=2; overwritten in place by logs)
//   sumsq : [3][4096]        (||log||_F^2 per matrix)
//   attn  : [32][128][128]
// mean_log reuses the logQ region (dead after k_attn).
constexpr size_t OFF_SS   = (size_t)3 * kNMAT * kMSZ;
constexpr size_t OFF_ATTN = OFF_SS + (size_t)3 * kNMAT;
// total = (12582912 + 12288 + 524288)*4 B ~= 52.5 MB of d_ws

#define F4(p)  (*(float4*)(p))
#define CF4(p) (*(const float4*)(p))

// ---------------------------------------------------------------- bimap ----
// P_t = W_t^T X W_t for t in {Q,K,V}; one block per (b,m).
__global__ __launch_bounds__(256) void k_bimap(
    const float* __restrict__ x, const float* __restrict__ Wq,
    const float* __restrict__ Wk, const float* __restrict__ Wv,
    float* __restrict__ P) {
  __shared__ float Xs[64 * 68];   // X, row-major padded
  __shared__ float Wsh[64 * 32];  // current W, row-major
  __shared__ float Ts[64 * 36];   // T = X*W, padded
  const int t = threadIdx.x;
  const int bm = blockIdx.x;
  const float* xp = x + (size_t)bm * (kDIN * kDIN);
  {
    const int f0 = t * 16;
    const int r = f0 >> 6, c = f0 & 63;
    const float* src = xp + f0;
    float* dst = &Xs[r * 68 + c];
#pragma unroll
    for (int i = 0; i < 4; ++i) F4(dst + 4 * i) = CF4(src + 4 * i);
  }
  const int r0 = (t >> 3) * 2;   // stage-1 rows
  const int j0 = (t & 7) * 4;    // output cols
  const int i2 = t >> 3;         // stage-2 row
  for (int tt = 0; tt < 3; ++tt) {
    const float* W = (tt == 0) ? Wq : ((tt == 1) ? Wk : Wv);
    __syncthreads();  // protect Wsh/Ts from previous type (also covers Xs @ tt=0)
    F4(&Wsh[t * 8]) = CF4(W + t * 8);
    F4(&Wsh[t * 8 + 4]) = CF4(W + t * 8 + 4);
    __syncthreads();
    // stage 1: T = X * W   (64x32)
    float a0[4] = {0.f, 0.f, 0.f, 0.f}, a1[4] = {0.f, 0.f, 0.f, 0.f};
    for (int k = 0; k < 64; ++k) {
      const float x0 = Xs[r0 * 68 + k];
      const float x1 = Xs[(r0 + 1) * 68 + k];
      const float4 w = CF4(&Wsh[k * 32 + j0]);
      a0[0] += x0 * w.x; a0[1] += x0 * w.y; a0[2] += x0 * w.z; a0[3] += x0 * w.w;
      a1[0] += x1 * w.x; a1[1] += x1 * w.y; a1[2] += x1 * w.z; a1[3] += x1 * w.w;
    }
    F4(&Ts[r0 * 36 + j0])       = make_float4(a0[0], a0[1], a0[2], a0[3]);
    F4(&Ts[(r0 + 1) * 36 + j0]) = make_float4(a1[0], a1[1], a1[2], a1[3]);
    __syncthreads();
    // stage 2: P = W^T * T  (32x32)
    float b4[4] = {0.f, 0.f, 0.f, 0.f};
    for (int p = 0; p < 64; ++p) {
      const float wv = Wsh[p * 32 + i2];
      const float4 tv = CF4(&Ts[p * 36 + j0]);
      b4[0] += wv * tv.x; b4[1] += wv * tv.y; b4[2] += wv * tv.z; b4[3] += wv * tv.w;
    }
    F4(&P[((size_t)tt * kNMAT + bm) * kMSZ + i2 * 32 + j0]) =
        make_float4(b4[0], b4[1], b4[2], b4[3]);
  }
}

// ----------------------------------------------------- one-sided Jacobi ----
// In-place: A (SPD 32x32) -> log(A). Also writes sumsq = ||log A||_F^2.
// One wave per matrix. Columns in LDS (stride 36 f32). After convergence the
// columns are sigma_i * u_i, so log A = B diag(log sigma / sigma^2) B^T.
__global__ __launch_bounds__(64) void k_jacobi_log(float* __restrict__ P,
                                                   float* __restrict__ sq) {
  __shared__ float Bs[32 * 36];
  __shared__ float wcol[32];
  const int lane = threadIdx.x;
  const size_t gid = blockIdx.x;  // type*4096 + bm
  float* A = P + gid * kMSZ;
  {  // load + transpose to column-major
    const int r = lane >> 1, c0 = (lane & 1) * 16;
    const float* Ar = A + r * 32 + c0;
#pragma unroll
    for (int i = 0; i < 16; i += 4) {
      const float4 v = CF4(Ar + i);
      Bs[(c0 + i + 0) * 36 + r] = v.x;
      Bs[(c0 + i + 1) * 36 + r] = v.y;
      Bs[(c0 + i + 2) * 36 + r] = v.z;
      Bs[(c0 + i + 3) * 36 + r] = v.w;
    }
  }
  __syncthreads();
  const int kp = lane >> 2;        // pair index 0..15
  const int off = (lane & 3) * 8;  // row quarter
  for (int sw = 0; sw < kNSweep; ++sw) {
    for (int r = 0; r < 31; ++r) {
      int p, q;
      if (kp == 0) { p = 31; q = r; }
      else { p = (r + kp) % 31; q = (r - kp + 31) % 31; }
      float* colp = &Bs[p * 36 + off];
      float* colq = &Bs[q * 36 + off];
      float bp[8], bq[8];
      { float4 v = CF4(colp);     bp[0]=v.x; bp[1]=v.y; bp[2]=v.z; bp[3]=v.w;
        v = CF4(colp + 4);        bp[4]=v.x; bp[5]=v.y; bp[6]=v.z; bp[7]=v.w;
        v = CF4(colq);            bq[0]=v.x; bq[1]=v.y; bq[2]=v.z; bq[3]=v.w;
        v = CF4(colq + 4);        bq[4]=v.x; bq[5]=v.y; bq[6]=v.z; bq[7]=v.w; }
      float app = 0.f, aqq = 0.f, apq = 0.f;
#pragma unroll
      for (int i = 0; i < 8; ++i) {
        app += bp[i] * bp[i];
        aqq += bq[i] * bq[i];
        apq += bp[i] * bq[i];
      }
      app += __shfl_xor(app, 1); app += __shfl_xor(app, 2);
      aqq += __shfl_xor(aqq, 1); aqq += __shfl_xor(aqq, 2);
      apq += __shfl_xor(apq, 1); apq += __shfl_xor(apq, 2);
      float c = 1.f, sn = 0.f;
      if (apq != 0.f) {
        const float tau = (aqq - app) / (2.f * apq);
        const float tt = copysignf(1.f, tau) / (fabsf(tau) + sqrtf(1.f + tau * tau));
        c = 1.f / sqrtf(1.f + tt * tt);
        sn = tt * c;
      }
      float np[8], nq[8];
#pragma unroll
      for (int i = 0; i < 8; ++i) {
        np[i] = c * bp[i] - sn * bq[i];
        nq[i] = sn * bp[i] + c * bq[i];
      }
      F4(colp)     = make_float4(np[0], np[1], np[2], np[3]);
      F4(colp + 4) = make_float4(np[4], np[5], np[6], np[7]);
      F4(colq)     = make_float4(nq[0], nq[1], nq[2], nq[3]);
      F4(colq + 4) = make_float4(nq[4], nq[5], nq[6], nq[7]);
      __syncthreads();
    }
  }
  {  // column norms -> sigma^2; w_c = log(sigma)/sigma^2; sumsq = sum (log sigma)^2
    const int c = lane & 31, h = lane >> 5;
    const float* col = &Bs[c * 36 + h * 16];
    float ssum = 0.f;
#pragma unroll
    for (int i = 0; i < 16; i += 4) {
      const float4 v = CF4(col + i);
      ssum += v.x * v.x + v.y * v.y + v.z * v.z + v.w * v.w;
    }
    ssum += __shfl_xor(ssum, 32);
    const float lg = 0.5f * logf(ssum);  // log sigma_c
    float tot = lg * lg;
    tot += __shfl_xor(tot, 1);  tot += __shfl_xor(tot, 2);
    tot += __shfl_xor(tot, 4);  tot += __shfl_xor(tot, 8);
    tot += __shfl_xor(tot, 16); tot += __shfl_xor(tot, 32);
    if (lane == 0) sq[gid] = 0.5f * tot;  // each column counted twice
    if (h == 0) wcol[c] = lg / ssum;
  }
  __syncthreads();
  {  // log A = B diag(w) B^T, 4x4 tile per lane, write back to global (row-major)
    const int rr = (lane >> 3) * 4, cc = (lane & 7) * 4;
    float acc[4][4] = {};
    for (int c = 0; c < 32; ++c) {
      const float w = wcol[c];
      const float4 br = CF4(&Bs[c * 36 + rr]);
      const float4 bc = CF4(&Bs[c * 36 + cc]);
      const float wr[4]  = {w * br.x, w * br.y, w * br.z, w * br.w};
      const float bcv[4] = {bc.x, bc.y, bc.z, bc.w};
#pragma unroll
      for (int i = 0; i < 4; ++i)
#pragma unroll
        for (int j2 = 0; j2 < 4; ++j2) acc[i][j2] += wr[i] * bcv[j2];
    }
#pragma unroll
    for (int i = 0; i < 4; ++i)
      F4(&A[(rr + i) * 32 + cc]) =
          make_float4(acc[i][0], acc[i][1], acc[i][2], acc[i][3]);
  }
}

// ------------------------------------------------- scores/softmax/attn ----
// Block: (jt, b); computes scores[i=0..127][j in 32-wide tile], softmax over i,
// writes attn[b][j][i].
__global__ __launch_bounds__(256) void k_attn(
    const float* __restrict__ P, const float* __restrict__ sq,
    float* __restrict__ attn) {
  __shared__ float Ks[128 * 36];  // logK chunk, later reused for scores
  __shared__ float Qs[32 * 36];
  __shared__ float red[8 * 36];
  __shared__ float mcol[32];
  __shared__ float scol[32];
  const int t = threadIdx.x;
  const int b = blockIdx.y, jt = blockIdx.x;
  const int j0g = jt * 32;
  const float* logK = P + ((size_t)kNMAT + (size_t)b * kM) * kMSZ;
  const float* logQ = P + ((size_t)b * kM + j0g) * kMSZ;
  const int i0 = (t >> 3) * 4, j0 = (t & 7) * 4;
  float acc[4][4] = {};
  for (int dc = 0; dc < kMSZ; dc += 32) {
    __syncthreads();
    {  // stage logK rows 0..127, cols dc..dc+31
      const int r = t >> 1, c0 = (t & 1) * 16;
      const float* src = logK + (size_t)r * kMSZ + dc + c0;
      float* dst = &Ks[r * 36 + c0];
#pragma unroll
      for (int i = 0; i < 4; ++i) F4(dst + 4 * i) = CF4(src + 4 * i);
    }
    {  // stage logQ tile rows
      const int r = t >> 3, c0 = (t & 7) * 4;
      F4(&Qs[r * 36 + c0]) = CF4(logQ + (size_t)r * kMSZ + dc + c0);
    }
    __syncthreads();
    for (int k = 0; k < 32; ++k) {
      float kv[4], qv[4];
#pragma unroll
      for (int i = 0; i < 4; ++i) kv[i] = Ks[(i0 + i) * 36 + k];
#pragma unroll
      for (int j2 = 0; j2 < 4; ++j2) qv[j2] = Qs[(j0 + j2) * 36 + k];
#pragma unroll
      for (int i = 0; i < 4; ++i)
#pragma unroll
        for (int j2 = 0; j2 < 4; ++j2) acc[i][j2] += kv[i] * qv[j2];
    }
  }
  __syncthreads();
  {  // energy -> scores, into Ks[i][jl]
    float k2v[4], q2v[4];
#pragma unroll
    for (int i = 0; i < 4; ++i) k2v[i] = sq[kNMAT + b * kM + i0 + i];
#pragma unroll
    for (int j2 = 0; j2 < 4; ++j2) q2v[j2] = sq[b * kM + j0g + j0 + j2];
#pragma unroll
    for (int i = 0; i < 4; ++i)
#pragma unroll
      for (int j2 = 0; j2 < 4; ++j2) {
        float e = k2v[i] + q2v[j2] - 2.f * acc[i][j2];
        e = fmaxf(e, 0.f);
        Ks[(i0 + i) * 36 + (j0 + j2)] = 1.f / (1.f + log1pf(e));
      }
  }
  __syncthreads();
  const int jl = t & 31, grp = t >> 5;
  {
    float m = -1e30f;
    for (int i = grp * 16; i < grp * 16 + 16; ++i) m = fmaxf(m, Ks[i * 36 + jl]);
    red[grp * 36 + jl] = m;
  }
  __syncthreads();
  if (t < 32) {
    float m = red[t];
#pragma unroll
    for (int g = 1; g < 8; ++g) m = fmaxf(m, red[g * 36 + t]);
    mcol[t] = m;
  }
  __syncthreads();
  {
    const float mj = mcol[jl];
    float s = 0.f;
    for (int i = grp * 16; i < grp * 16 + 16; ++i) s += expf(Ks[i * 36 + jl] - mj);
    red[grp * 36 + jl] = s;
  }
  __syncthreads();
  if (t < 32) {
    float s = red[t];
#pragma unroll
    for (int g = 1; g < 8; ++g) s += red[g * 36 + t];
    scol[t] = 1.f / s;
  }
  __syncthreads();
  {  // write attn[b][j][i], coalesced in i
    const int il = t & 31, jg = t >> 5;
#pragma unroll
    for (int rep = 0; rep < 4; ++rep) {
      const int j2 = jg + rep * 8;
      const float mj = mcol[j2], is = scol[j2];
      float* dst = attn + ((size_t)b * kM + j0g + j2) * kM;
#pragma unroll
      for (int c4 = 0; c4 < 4; ++c4) {
        const int i = il + c4 * 32;
        dst[i] = expf(Ks[i * 36 + j2] - mj) * is;
      }
    }
  }
}

// -------------------------------------------------------------- meanlog ----
// ML[b][j][:] = sum_i attn[b][j][i] * logV[b][i][:]   (GEMM 32x1024, K=128)
__global__ __launch_bounds__(256) void k_meanlog(
    const float* __restrict__ attn, const float* __restrict__ P,
    float* __restrict__ ML) {
  __shared__ float As[32 * 132];
  __shared__ float Vs[128 * 64];
  const int t = threadIdx.x;
  const int b = blockIdx.y, jt = blockIdx.x;
  const int j0g = jt * 32;
  const float* logV = P + ((size_t)2 * kNMAT + (size_t)b * kM) * kMSZ;
  {  // stage attn tile [32][128]
    const int r = t >> 3, c0 = (t & 7) * 16;
    const float* src = attn + ((size_t)b * kM + j0g + r) * kM + c0;
    float* dst = &As[r * 132 + c0];
#pragma unroll
    for (int i = 0; i < 4; ++i) F4(dst + 4 * i) = CF4(src + 4 * i);
  }
  const int j0 = (t >> 4) * 2, d0 = (t & 15) * 4;
  for (int dc = 0; dc < kMSZ; dc += 64) {
    __syncthreads();
    {  // stage logV[k=0..127][dc..dc+63]
      const int r = t >> 1, c0 = (t & 1) * 32;
      const float* src = logV + (size_t)r * kMSZ + dc + c0;
      float* dst = &Vs[r * 64 + c0];
#pragma unroll
      for (int i = 0; i < 8; ++i) F4(dst + 4 * i) = CF4(src + 4 * i);
    }
    __syncthreads();
    float a0[4] = {0.f,0.f,0.f,0.f}, a1[4] = {0.f,0.f,0.f,0.f};
    for (int k = 0; k < kM; ++k) {
      const float w0 = As[(j0 + 0) * 132 + k];
      const float w1 = As[(j0 + 1) * 132 + k];
      const float4 v = CF4(&Vs[k * 64 + d0]);
      a0[0] += w0 * v.x; a0[1] += w0 * v.y; a0[2] += w0 * v.z; a0[3] += w0 * v.w;
      a1[0] += w1 * v.x; a1[1] += w1 * v.y; a1[2] += w1 * v.z; a1[3] += w1 * v.w;
    }
    F4(&ML[((size_t)b * kM + j0g + j0 + 0) * kMSZ + dc + d0]) =
        make_float4(a0[0], a0[1], a0[2], a0[3]);
    F4(&ML[((size_t)b * kM + j0g + j0 + 1) * kMSZ + dc + d0]) =
        make_float4(a1[0], a1[1], a1[2], a1[3]);
  }
}

// ------------------------------------------------------------------ exp ----
// out = exp(S): scaling-and-squaring + degree-10 Horner Taylor. One wave per matrix.
__global__ __launch_bounds__(64) void k_expm(const float* __restrict__ ML,
                                             float* __restrict__ out) {
  __shared__ float Mb[32 * 36];
  __shared__ float Tb[2][32 * 36];
  const int lane = threadIdx.x;
  const size_t bm = blockIdx.x;
  const float* S = ML + bm * kMSZ;
  const int r = lane >> 1, c0 = (lane & 1) * 16;
  float lsum = 0.f;
#pragma unroll
  for (int i = 0; i < 16; i += 4) {
    const float4 v = CF4(S + r * 32 + c0 + i);
    F4(&Mb[r * 36 + c0 + i]) = v;
    lsum += v.x * v.x + v.y * v.y + v.z * v.z + v.w * v.w;
  }
#pragma unroll
  for (int d = 1; d < 64; d <<= 1) lsum += __shfl_xor(lsum, d);
  const float fn = sqrtf(lsum);     // Frobenius norm >= spectral norm
  int sc = 0;
  if (fn > 0.5f) sc = (int)ceilf(log2f(fn * 2.0f));
  const float scale = exp2f((float)(-sc));
  __syncthreads();
#pragma unroll
  for (int i = 0; i < 16; i += 4) {
    float4 v = F4(&Mb[r * 36 + c0 + i]);
    v.x *= scale; v.y *= scale; v.z *= scale; v.w *= scale;
    F4(&Mb[r * 36 + c0 + i]) = v;
  }
  __syncthreads();
  const int rr = (lane >> 3) * 4, cc = (lane & 7) * 4;
#pragma unroll
  for (int i = 0; i < 4; ++i) {  // T = I + M/10
    float4 v = F4(&Mb[(rr + i) * 36 + cc]);
    v.x = v.x * 0.1f + ((rr + i == cc + 0) ? 1.f : 0.f);
    v.y = v.y * 0.1f + ((rr + i == cc + 1) ? 1.f : 0.f);
    v.z = v.z * 0.1f + ((rr + i == cc + 2) ? 1.f : 0.f);
    v.w = v.w * 0.1f + ((rr + i == cc + 3) ? 1.f : 0.f);
    F4(&Tb[0][(rr + i) * 36 + cc]) = v;
  }
  __syncthreads();
  int cur = 0;
  for (int j = 9; j >= 1; --j) {  // T <- I + (M*T)/j
    float a4[4][4] = {};
    for (int k = 0; k < 32; ++k) {
      float mv[4];
#pragma unroll
      for (int i = 0; i < 4; ++i) mv[i] = Mb[(rr + i) * 36 + k];
      const float4 tv = CF4(&Tb[cur][k * 36 + cc]);
      const float tvv[4] = {tv.x, tv.y, tv.z, tv.w};
#pragma unroll
      for (int i = 0; i < 4; ++i)
#pragma unroll
        for (int j2 = 0; j2 < 4; ++j2) a4[i][j2] += mv[i] * tvv[j2];
    }
    const float inv = 1.f / (float)j;
#pragma unroll
    for (int i = 0; i < 4; ++i) {
      float4 v;
      v.x = a4[i][0] * inv + ((rr + i == cc + 0) ? 1.f : 0.f);
      v.y = a4[i][1] * inv + ((rr + i == cc + 1) ? 1.f : 0.f);
      v.z = a4[i][2] * inv + ((rr + i == cc + 2) ? 1.f : 0.f);
      v.w = a4[i][3] * inv + ((rr + i == cc + 3) ? 1.f : 0.f);
      F4(&Tb[cur ^ 1][(rr + i) * 36 + cc]) = v;
    }
    __syncthreads();
    cur ^= 1;
  }
  for (int st = 0; st < sc; ++st) {  // T <- T*T
    float a4[4][4] = {};
    for (int k = 0; k < 32; ++k) {
      float mv[4];
#pragma unroll
      for (int i = 0; i < 4; ++i) mv[i] = Tb[cur][(rr + i) * 36 + k];
      const float4 tv = CF4(&Tb[cur][k * 36 + cc]);
      const float tvv[4] = {tv.x, tv.y, tv.z, tv.w};
#pragma unroll
      for (int i = 0; i < 4; ++i)
#pragma unroll
        for (int j2 = 0; j2 < 4; ++j2) a4[i][j2] += mv[i] * tvv[j2];
    }
#pragma unroll
    for (int i = 0; i < 4; ++i)
      F4(&Tb[cur ^ 1][(rr + i) * 36 + cc]) =
          make_float4(a4[i][0], a4[i][1], a4[i][2], a4[i][3]);
    __syncthreads();
    cur ^= 1;
  }
#pragma unroll
  for (int i = 0; i < 4; ++i) {
    const float4 v = CF4(&Tb[cur][(rr + i) * 36 + cc]);
    F4(&out[bm * kMSZ + (rr + i) * 32 + cc]) = v;
  }
}

// -------------------------------------------------------------- launch ----
extern "C" void kernel_launch(void* const* d_in, const int* in_sizes, int n_in,
                              void* d_out, int out_size, void* d_ws, size_t ws_size,
                              hipStream_t stream) {
  const float* x  = (const float*)d_in[0];
  const float* Wq = (const float*)d_in[1];
  const float* Wk = (const float*)d_in[2];
  const float* Wv = (const float*)d_in[3];
  float* ws   = (float*)d_ws;
  float* P    = ws;                 // [3][4096][1024]
  float* sq   = ws + OFF_SS;        // [3][4096]
  float* attn = ws + OFF_ATTN;      // [32][128][128]
  float* ML   = ws;                 // reuse logQ region (dead after k_attn)
  float* out  = (float*)d_out;

  k_bimap<<<kNMAT, 256, 0, stream>>>(x, Wq, Wk, Wv, P);
  k_jacobi_log<<<3 * kNMAT, 64, 0, stream>>>(P, sq);
  k_attn<<<dim3(4, kBS), 256, 0, stream>>>(P, sq, attn);
  k_meanlog<<<dim3(4, kBS), 256, 0, stream>>>(attn, P, ML);
  k_expm<<<kNMAT, 64, 0, stream>>>(ML, out);
}

// Round 2
// 829.425 us; speedup vs baseline: 1.2800x; 1.2800x over previous
//
#include <hip/hip_runtime.h>
#include <math.h>

// Problem constants
constexpr int kBS = 32, kM = 128, kNMAT = kBS * kM;         // 4096 (b,m) pairs
constexpr int kDIN = 64, kDOUT = 32, kMSZ = kDOUT * kDOUT;  // 1024 floats per 32x32
constexpr int kNSweep = 8;                                  // Jacobi sweeps (fixed, deterministic)

// ws layout (floats):
//   P/log : [3][4096][1024]  (Q=0,K=1,V=2; overwritten in place by logs)
//   sumsq : [3][4096]        (||log||_F^2 per matrix)
//   attn  : [32][128][128]
// mean_log reuses the logQ region (dead after k_attn).
constexpr size_t OFF_SS   = (size_t)3 * kNMAT * kMSZ;
constexpr size_t OFF_ATTN = OFF_SS + (size_t)3 * kNMAT;

#define F4(p)  (*(float4*)(p))
#define CF4(p) (*(const float4*)(p))

// ---------------------------------------------------------------- bimap ----
// P_t = W_t^T X W_t for t in {Q,K,V}; one block per (b,m).
__global__ __launch_bounds__(256) void k_bimap(
    const float* __restrict__ x, const float* __restrict__ Wq,
    const float* __restrict__ Wk, const float* __restrict__ Wv,
    float* __restrict__ P) {
  __shared__ float Xs[64 * 68];   // X, row-major padded
  __shared__ float Wsh[64 * 32];  // current W, row-major
  __shared__ float Ts[64 * 36];   // T = X*W, padded
  const int t = threadIdx.x;
  const int bm = blockIdx.x;
  const float* xp = x + (size_t)bm * (kDIN * kDIN);
  {
    const int f0 = t * 16;
    const int r = f0 >> 6, c = f0 & 63;
    const float* src = xp + f0;
    float* dst = &Xs[r * 68 + c];
#pragma unroll
    for (int i = 0; i < 4; ++i) F4(dst + 4 * i) = CF4(src + 4 * i);
  }
  const int r0 = (t >> 3) * 2;   // stage-1 rows
  const int j0 = (t & 7) * 4;    // output cols
  const int i2 = t >> 3;         // stage-2 row
  for (int tt = 0; tt < 3; ++tt) {
    const float* W = (tt == 0) ? Wq : ((tt == 1) ? Wk : Wv);
    __syncthreads();  // protect Wsh/Ts from previous type (also covers Xs @ tt=0)
    F4(&Wsh[t * 8]) = CF4(W + t * 8);
    F4(&Wsh[t * 8 + 4]) = CF4(W + t * 8 + 4);
    __syncthreads();
    // stage 1: T = X * W   (64x32)
    float a0[4] = {0.f, 0.f, 0.f, 0.f}, a1[4] = {0.f, 0.f, 0.f, 0.f};
    for (int k = 0; k < 64; ++k) {
      const float x0 = Xs[r0 * 68 + k];
      const float x1 = Xs[(r0 + 1) * 68 + k];
      const float4 w = CF4(&Wsh[k * 32 + j0]);
      a0[0] += x0 * w.x; a0[1] += x0 * w.y; a0[2] += x0 * w.z; a0[3] += x0 * w.w;
      a1[0] += x1 * w.x; a1[1] += x1 * w.y; a1[2] += x1 * w.z; a1[3] += x1 * w.w;
    }
    F4(&Ts[r0 * 36 + j0])       = make_float4(a0[0], a0[1], a0[2], a0[3]);
    F4(&Ts[(r0 + 1) * 36 + j0]) = make_float4(a1[0], a1[1], a1[2], a1[3]);
    __syncthreads();
    // stage 2: P = W^T * T  (32x32)
    float b4[4] = {0.f, 0.f, 0.f, 0.f};
    for (int p = 0; p < 64; ++p) {
      const float wv = Wsh[p * 32 + i2];
      const float4 tv = CF4(&Ts[p * 36 + j0]);
      b4[0] += wv * tv.x; b4[1] += wv * tv.y; b4[2] += wv * tv.z; b4[3] += wv * tv.w;
    }
    F4(&P[((size_t)tt * kNMAT + bm) * kMSZ + i2 * 32 + j0]) =
        make_float4(b4[0], b4[1], b4[2], b4[3]);
  }
}

// ----------------------------------------------------- one-sided Jacobi ----
// In-place: A (SPD 32x32) -> log(A). Also writes sumsq = ||log A||_F^2.
// 4 waves per block, ONE MATRIX PER WAVE in a private LDS slot; no s_barrier
// anywhere (wave-lockstep + in-order DS + wave_barrier compiler fences).
// Columns in LDS (stride 36 f32). After convergence the columns are
// sigma_i * u_i, so log A = B diag(log sigma / sigma^2) B^T.
// Per-column squared norms are maintained analytically in LDS (rotation
// preserves app+aqq), so each round only needs the apq dot product.
constexpr int kJSlot = 32 * 36 + 32;  // 1152 col data + 32 norms = 1184 floats

__global__ __launch_bounds__(256, 8) void k_jacobi_log(float* __restrict__ P,
                                                       float* __restrict__ sq) {
  __shared__ float lds[4 * kJSlot];
  const int t = threadIdx.x;
  const int wid = t >> 6, lane = t & 63;
  const size_t gid = (size_t)blockIdx.x * 4 + wid;  // type*4096 + bm
  float* A = P + gid * kMSZ;
  float* Bs = lds + wid * kJSlot;
  float* ncol = Bs + 1152;  // per-column squared norms; reused as wcol at end
  {  // load + transpose to column-major
    const int r = lane >> 1, c0 = (lane & 1) * 16;
    const float* Ar = A + r * 32 + c0;
#pragma unroll
    for (int i = 0; i < 16; i += 4) {
      const float4 v = CF4(Ar + i);
      Bs[(c0 + i + 0) * 36 + r] = v.x;
      Bs[(c0 + i + 1) * 36 + r] = v.y;
      Bs[(c0 + i + 2) * 36 + r] = v.z;
      Bs[(c0 + i + 3) * 36 + r] = v.w;
    }
  }
  __builtin_amdgcn_wave_barrier();
  {  // initial column squared norms
    const int c = lane & 31, h = lane >> 5;
    const float* col = &Bs[c * 36 + h * 16];
    float ssum = 0.f;
#pragma unroll
    for (int i = 0; i < 16; i += 4) {
      const float4 v = CF4(col + i);
      ssum += v.x * v.x + v.y * v.y + v.z * v.z + v.w * v.w;
    }
    ssum += __shfl_xor(ssum, 32);
    if (h == 0) ncol[c] = ssum;
  }
  __builtin_amdgcn_wave_barrier();
  const int kp = lane >> 2;        // pair index 0..15
  const int off = (lane & 3) * 8;  // row quarter
  for (int sw = 0; sw < kNSweep; ++sw) {
    for (int r = 0; r < 31; ++r) {
      int p, q;
      if (kp == 0) {
        p = 31; q = r;
      } else {
        p = r + kp; if (p >= 31) p -= 31;
        q = r - kp; if (q < 0)  q += 31;
      }
      float* colp = &Bs[p * 36 + off];
      float* colq = &Bs[q * 36 + off];
      float bp[8], bq[8];
      { float4 v = CF4(colp);     bp[0]=v.x; bp[1]=v.y; bp[2]=v.z; bp[3]=v.w;
        v = CF4(colp + 4);        bp[4]=v.x; bp[5]=v.y; bp[6]=v.z; bp[7]=v.w;
        v = CF4(colq);            bq[0]=v.x; bq[1]=v.y; bq[2]=v.z; bq[3]=v.w;
        v = CF4(colq + 4);        bq[4]=v.x; bq[5]=v.y; bq[6]=v.z; bq[7]=v.w; }
      const float app = ncol[p];
      const float aqq = ncol[q];
      float apq = 0.f;
#pragma unroll
      for (int i = 0; i < 8; ++i) apq += bp[i] * bq[i];
      apq += __shfl_xor(apq, 1);
      apq += __shfl_xor(apq, 2);
      // branchless rotation (guarded against 0/0)
      float denom = 2.f * apq;
      denom = (denom == 0.f) ? 1e-30f : denom;
      const float tau = (aqq - app) * __builtin_amdgcn_rcpf(denom);
      const float tt = copysignf(1.f, tau) *
          __builtin_amdgcn_rcpf(fabsf(tau) + __builtin_amdgcn_sqrtf(fmaf(tau, tau, 1.f)));
      const float c = __builtin_amdgcn_rsqf(fmaf(tt, tt, 1.f));
      const float sn = tt * c;
      float np[8], nq[8];
#pragma unroll
      for (int i = 0; i < 8; ++i) {
        np[i] = c * bp[i] - sn * bq[i];
        nq[i] = sn * bp[i] + c * bq[i];
      }
      F4(colp)     = make_float4(np[0], np[1], np[2], np[3]);
      F4(colp + 4) = make_float4(np[4], np[5], np[6], np[7]);
      F4(colq)     = make_float4(nq[0], nq[1], nq[2], nq[3]);
      F4(colq + 4) = make_float4(nq[4], nq[5], nq[6], nq[7]);
      if ((lane & 3) == 0) {  // analytic norm update (rotation preserves sum)
        const float capp = c * c * app + sn * sn * aqq - 2.f * c * sn * apq;
        ncol[p] = capp;
        ncol[q] = app + aqq - capp;
      }
      __builtin_amdgcn_wave_barrier();
    }
  }
  float wreg;  // this lane's wcol value staging (avoid read-after-write hazard)
  {  // exact column norms -> sigma^2; w_c = log(sigma)/sigma^2; sumsq
    const int c = lane & 31, h = lane >> 5;
    const float* col = &Bs[c * 36 + h * 16];
    float ssum = 0.f;
#pragma unroll
    for (int i = 0; i < 16; i += 4) {
      const float4 v = CF4(col + i);
      ssum += v.x * v.x + v.y * v.y + v.z * v.z + v.w * v.w;
    }
    ssum += __shfl_xor(ssum, 32);
    const float lg = 0.5f * logf(ssum);  // log sigma_c
    float tot = lg * lg;
    tot += __shfl_xor(tot, 1);  tot += __shfl_xor(tot, 2);
    tot += __shfl_xor(tot, 4);  tot += __shfl_xor(tot, 8);
    tot += __shfl_xor(tot, 16); tot += __shfl_xor(tot, 32);
    if (lane == 0) sq[gid] = 0.5f * tot;  // each column counted twice
    wreg = lg / ssum;
    if (h == 0) ncol[c] = wreg;  // ncol now holds wcol
  }
  __builtin_amdgcn_wave_barrier();
  {  // log A = B diag(w) B^T, 4x4 tile per lane, write back to global (row-major)
    const int rr = (lane >> 3) * 4, cc = (lane & 7) * 4;
    float acc[4][4] = {};
    for (int c = 0; c < 32; ++c) {
      const float w = ncol[c];
      const float4 br = CF4(&Bs[c * 36 + rr]);
      const float4 bc = CF4(&Bs[c * 36 + cc]);
      const float wr[4]  = {w * br.x, w * br.y, w * br.z, w * br.w};
      const float bcv[4] = {bc.x, bc.y, bc.z, bc.w};
#pragma unroll
      for (int i = 0; i < 4; ++i)
#pragma unroll
        for (int j2 = 0; j2 < 4; ++j2) acc[i][j2] += wr[i] * bcv[j2];
    }
#pragma unroll
    for (int i = 0; i < 4; ++i)
      F4(&A[(rr + i) * 32 + cc]) =
          make_float4(acc[i][0], acc[i][1], acc[i][2], acc[i][3]);
  }
}

// ------------------------------------------------- scores/softmax/attn ----
// Block: (jt, b); computes scores[i=0..127][j in 32-wide tile], softmax over i,
// writes attn[b][j][i].
__global__ __launch_bounds__(256) void k_attn(
    const float* __restrict__ P, const float* __restrict__ sq,
    float* __restrict__ attn) {
  __shared__ float Ks[128 * 36];  // logK chunk, later reused for scores
  __shared__ float Qs[32 * 36];
  __shared__ float red[8 * 36];
  __shared__ float mcol[32];
  __shared__ float scol[32];
  const int t = threadIdx.x;
  const int b = blockIdx.y, jt = blockIdx.x;
  const int j0g = jt * 32;
  const float* logK = P + ((size_t)kNMAT + (size_t)b * kM) * kMSZ;
  const float* logQ = P + ((size_t)b * kM + j0g) * kMSZ;
  const int i0 = (t >> 3) * 4, j0 = (t & 7) * 4;
  float acc[4][4] = {};
  for (int dc = 0; dc < kMSZ; dc += 32) {
    __syncthreads();
    {  // stage logK rows 0..127, cols dc..dc+31
      const int r = t >> 1, c0 = (t & 1) * 16;
      const float* src = logK + (size_t)r * kMSZ + dc + c0;
      float* dst = &Ks[r * 36 + c0];
#pragma unroll
      for (int i = 0; i < 4; ++i) F4(dst + 4 * i) = CF4(src + 4 * i);
    }
    {  // stage logQ tile rows
      const int r = t >> 3, c0 = (t & 7) * 4;
      F4(&Qs[r * 36 + c0]) = CF4(logQ + (size_t)r * kMSZ + dc + c0);
    }
    __syncthreads();
    for (int k = 0; k < 32; ++k) {
      float kv[4], qv[4];
#pragma unroll
      for (int i = 0; i < 4; ++i) kv[i] = Ks[(i0 + i) * 36 + k];
#pragma unroll
      for (int j2 = 0; j2 < 4; ++j2) qv[j2] = Qs[(j0 + j2) * 36 + k];
#pragma unroll
      for (int i = 0; i < 4; ++i)
#pragma unroll
        for (int j2 = 0; j2 < 4; ++j2) acc[i][j2] += kv[i] * qv[j2];
    }
  }
  __syncthreads();
  {  // energy -> scores, into Ks[i][jl]
    float k2v[4], q2v[4];
#pragma unroll
    for (int i = 0; i < 4; ++i) k2v[i] = sq[kNMAT + b * kM + i0 + i];
#pragma unroll
    for (int j2 = 0; j2 < 4; ++j2) q2v[j2] = sq[b * kM + j0g + j0 + j2];
#pragma unroll
    for (int i = 0; i < 4; ++i)
#pragma unroll
      for (int j2 = 0; j2 < 4; ++j2) {
        float e = k2v[i] + q2v[j2] - 2.f * acc[i][j2];
        e = fmaxf(e, 0.f);
        Ks[(i0 + i) * 36 + (j0 + j2)] = 1.f / (1.f + log1pf(e));
      }
  }
  __syncthreads();
  const int jl = t & 31, grp = t >> 5;
  {
    float m = -1e30f;
    for (int i = grp * 16; i < grp * 16 + 16; ++i) m = fmaxf(m, Ks[i * 36 + jl]);
    red[grp * 36 + jl] = m;
  }
  __syncthreads();
  if (t < 32) {
    float m = red[t];
#pragma unroll
    for (int g = 1; g < 8; ++g) m = fmaxf(m, red[g * 36 + t]);
    mcol[t] = m;
  }
  __syncthreads();
  {
    const float mj = mcol[jl];
    float s = 0.f;
    for (int i = grp * 16; i < grp * 16 + 16; ++i) s += expf(Ks[i * 36 + jl] - mj);
    red[grp * 36 + jl] = s;
  }
  __syncthreads();
  if (t < 32) {
    float s = red[t];
#pragma unroll
    for (int g = 1; g < 8; ++g) s += red[g * 36 + t];
    scol[t] = 1.f / s;
  }
  __syncthreads();
  {  // write attn[b][j][i], coalesced in i
    const int il = t & 31, jg = t >> 5;
#pragma unroll
    for (int rep = 0; rep < 4; ++rep) {
      const int j2 = jg + rep * 8;
      const float mj = mcol[j2], is = scol[j2];
      float* dst = attn + ((size_t)b * kM + j0g + j2) * kM;
#pragma unroll
      for (int c4 = 0; c4 < 4; ++c4) {
        const int i = il + c4 * 32;
        dst[i] = expf(Ks[i * 36 + j2] - mj) * is;
      }
    }
  }
}

// -------------------------------------------------------------- meanlog ----
// ML[b][j][:] = sum_i attn[b][j][i] * logV[b][i][:]   (GEMM 32x1024, K=128)
__global__ __launch_bounds__(256) void k_meanlog(
    const float* __restrict__ attn, const float* __restrict__ P,
    float* __restrict__ ML) {
  __shared__ float As[32 * 132];
  __shared__ float Vs[128 * 64];
  const int t = threadIdx.x;
  const int b = blockIdx.y, jt = blockIdx.x;
  const int j0g = jt * 32;
  const float* logV = P + ((size_t)2 * kNMAT + (size_t)b * kM) * kMSZ;
  {  // stage attn tile [32][128]
    const int r = t >> 3, c0 = (t & 7) * 16;
    const float* src = attn + ((size_t)b * kM + j0g + r) * kM + c0;
    float* dst = &As[r * 132 + c0];
#pragma unroll
    for (int i = 0; i < 4; ++i) F4(dst + 4 * i) = CF4(src + 4 * i);
  }
  const int j0 = (t >> 4) * 2, d0 = (t & 15) * 4;
  for (int dc = 0; dc < kMSZ; dc += 64) {
    __syncthreads();
    {  // stage logV[k=0..127][dc..dc+63]
      const int r = t >> 1, c0 = (t & 1) * 32;
      const float* src = logV + (size_t)r * kMSZ + dc + c0;
      float* dst = &Vs[r * 64 + c0];
#pragma unroll
      for (int i = 0; i < 8; ++i) F4(dst + 4 * i) = CF4(src + 4 * i);
    }
    __syncthreads();
    float a0[4] = {0.f,0.f,0.f,0.f}, a1[4] = {0.f,0.f,0.f,0.f};
    for (int k = 0; k < kM; ++k) {
      const float w0 = As[(j0 + 0) * 132 + k];
      const float w1 = As[(j0 + 1) * 132 + k];
      const float4 v = CF4(&Vs[k * 64 + d0]);
      a0[0] += w0 * v.x; a0[1] += w0 * v.y; a0[2] += w0 * v.z; a0[3] += w0 * v.w;
      a1[0] += w1 * v.x; a1[1] += w1 * v.y; a1[2] += w1 * v.z; a1[3] += w1 * v.w;
    }
    F4(&ML[((size_t)b * kM + j0g + j0 + 0) * kMSZ + dc + d0]) =
        make_float4(a0[0], a0[1], a0[2], a0[3]);
    F4(&ML[((size_t)b * kM + j0g + j0 + 1) * kMSZ + dc + d0]) =
        make_float4(a1[0], a1[1], a1[2], a1[3]);
  }
}

// ------------------------------------------------------------------ exp ----
// out = exp(S): scaling-and-squaring + degree-10 Horner Taylor. One wave per matrix.
__global__ __launch_bounds__(64) void k_expm(const float* __restrict__ ML,
                                             float* __restrict__ out) {
  __shared__ float Mb[32 * 36];
  __shared__ float Tb[2][32 * 36];
  const int lane = threadIdx.x;
  const size_t bm = blockIdx.x;
  const float* S = ML + bm * kMSZ;
  const int r = lane >> 1, c0 = (lane & 1) * 16;
  float lsum = 0.f;
#pragma unroll
  for (int i = 0; i < 16; i += 4) {
    const float4 v = CF4(S + r * 32 + c0 + i);
    F4(&Mb[r * 36 + c0 + i]) = v;
    lsum += v.x * v.x + v.y * v.y + v.z * v.z + v.w * v.w;
  }
#pragma unroll
  for (int d = 1; d < 64; d <<= 1) lsum += __shfl_xor(lsum, d);
  const float fn = sqrtf(lsum);     // Frobenius norm >= spectral norm
  int sc = 0;
  if (fn > 0.5f) sc = (int)ceilf(log2f(fn * 2.0f));
  const float scale = exp2f((float)(-sc));
  __syncthreads();
#pragma unroll
  for (int i = 0; i < 16; i += 4) {
    float4 v = F4(&Mb[r * 36 + c0 + i]);
    v.x *= scale; v.y *= scale; v.z *= scale; v.w *= scale;
    F4(&Mb[r * 36 + c0 + i]) = v;
  }
  __syncthreads();
  const int rr = (lane >> 3) * 4, cc = (lane & 7) * 4;
#pragma unroll
  for (int i = 0; i < 4; ++i) {  // T = I + M/10
    float4 v = F4(&Mb[(rr + i) * 36 + cc]);
    v.x = v.x * 0.1f + ((rr + i == cc + 0) ? 1.f : 0.f);
    v.y = v.y * 0.1f + ((rr + i == cc + 1) ? 1.f : 0.f);
    v.z = v.z * 0.1f + ((rr + i == cc + 2) ? 1.f : 0.f);
    v.w = v.w * 0.1f + ((rr + i == cc + 3) ? 1.f : 0.f);
    F4(&Tb[0][(rr + i) * 36 + cc]) = v;
  }
  __syncthreads();
  int cur = 0;
  for (int j = 9; j >= 1; --j) {  // T <- I + (M*T)/j
    float a4[4][4] = {};
    for (int k = 0; k < 32; ++k) {
      float mv[4];
#pragma unroll
      for (int i = 0; i < 4; ++i) mv[i] = Mb[(rr + i) * 36 + k];
      const float4 tv = CF4(&Tb[cur][k * 36 + cc]);
      const float tvv[4] = {tv.x, tv.y, tv.z, tv.w};
#pragma unroll
      for (int i = 0; i < 4; ++i)
#pragma unroll
        for (int j2 = 0; j2 < 4; ++j2) a4[i][j2] += mv[i] * tvv[j2];
    }
    const float inv = 1.f / (float)j;
#pragma unroll
    for (int i = 0; i < 4; ++i) {
      float4 v;
      v.x = a4[i][0] * inv + ((rr + i == cc + 0) ? 1.f : 0.f);
      v.y = a4[i][1] * inv + ((rr + i == cc + 1) ? 1.f : 0.f);
      v.z = a4[i][2] * inv + ((rr + i == cc + 2) ? 1.f : 0.f);
      v.w = a4[i][3] * inv + ((rr + i == cc + 3) ? 1.f : 0.f);
      F4(&Tb[cur ^ 1][(rr + i) * 36 + cc]) = v;
    }
    __syncthreads();
    cur ^= 1;
  }
  for (int st = 0; st < sc; ++st) {  // T <- T*T
    float a4[4][4] = {};
    for (int k = 0; k < 32; ++k) {
      float mv[4];
#pragma unroll
      for (int i = 0; i < 4; ++i) mv[i] = Tb[cur][(rr + i) * 36 + k];
      const float4 tv = CF4(&Tb[cur][k * 36 + cc]);
      const float tvv[4] = {tv.x, tv.y, tv.z, tv.w};
#pragma unroll
      for (int i = 0; i < 4; ++i)
#pragma unroll
        for (int j2 = 0; j2 < 4; ++j2) a4[i][j2] += mv[i] * tvv[j2];
    }
#pragma unroll
    for (int i = 0; i < 4; ++i)
      F4(&Tb[cur ^ 1][(rr + i) * 36 + cc]) =
          make_float4(a4[i][0], a4[i][1], a4[i][2], a4[i][3]);
    __syncthreads();
    cur ^= 1;
  }
#pragma unroll
  for (int i = 0; i < 4; ++i) {
    const float4 v = CF4(&Tb[cur][(rr + i) * 36 + cc]);
    F4(&out[bm * kMSZ + (rr + i) * 32 + cc]) = v;
  }
}

// -------------------------------------------------------------- launch ----
extern "C" void kernel_launch(void* const* d_in, const int* in_sizes, int n_in,
                              void* d_out, int out_size, void* d_ws, size_t ws_size,
                              hipStream_t stream) {
  const float* x  = (const float*)d_in[0];
  const float* Wq = (const float*)d_in[1];
  const float* Wk = (const float*)d_in[2];
  const float* Wv = (const float*)d_in[3];
  float* ws   = (float*)d_ws;
  float* P    = ws;                 // [3][4096][1024]
  float* sq   = ws + OFF_SS;        // [3][4096]
  float* attn = ws + OFF_ATTN;      // [32][128][128]
  float* ML   = ws;                 // reuse logQ region (dead after k_attn)
  float* out  = (float*)d_out;

  k_bimap<<<kNMAT, 256, 0, stream>>>(x, Wq, Wk, Wv, P);
  k_jacobi_log<<<3 * kNMAT / 4, 256, 0, stream>>>(P, sq);
  k_attn<<<dim3(4, kBS), 256, 0, stream>>>(P, sq, attn);
  k_meanlog<<<dim3(4, kBS), 256, 0, stream>>>(attn, P, ML);
  k_expm<<<kNMAT, 64, 0, stream>>>(ML, out);
}

// Round 3
// 811.862 us; speedup vs baseline: 1.3077x; 1.0216x over previous
//
#include <hip/hip_runtime.h>
#include <math.h>

// Problem constants
constexpr int kBS = 32, kM = 128, kNMAT = kBS * kM;         // 4096 (b,m) pairs
constexpr int kDIN = 64, kDOUT = 32, kMSZ = kDOUT * kDOUT;  // 1024 floats per 32x32
constexpr int kNSweep = 8;                                  // Jacobi sweeps (fixed, deterministic)

// ws layout (floats):
//   P/log : [3][4096][1024]  (Q=0,K=1,V=2; overwritten in place by logs)
//   sumsq : [3][4096]        (||log||_F^2 per matrix)
//   attn  : [32][128][128]
// mean_log reuses the logQ region (dead after k_attn).
constexpr size_t OFF_SS   = (size_t)3 * kNMAT * kMSZ;
constexpr size_t OFF_ATTN = OFF_SS + (size_t)3 * kNMAT;

#define F4(p)  (*(float4*)(p))
#define CF4(p) (*(const float4*)(p))

// ---------------------------------------------------------------- bimap ----
// P_t = W_t^T X W_t for t in {Q,K,V}; one block per (b,m).
__global__ __launch_bounds__(256) void k_bimap(
    const float* __restrict__ x, const float* __restrict__ Wq,
    const float* __restrict__ Wk, const float* __restrict__ Wv,
    float* __restrict__ P) {
  __shared__ float Xs[64 * 68];   // X, row-major padded
  __shared__ float Wsh[64 * 32];  // current W, row-major
  __shared__ float Ts[64 * 36];   // T = X*W, padded
  const int t = threadIdx.x;
  const int bm = blockIdx.x;
  const float* xp = x + (size_t)bm * (kDIN * kDIN);
  {
    const int f0 = t * 16;
    const int r = f0 >> 6, c = f0 & 63;
    const float* src = xp + f0;
    float* dst = &Xs[r * 68 + c];
#pragma unroll
    for (int i = 0; i < 4; ++i) F4(dst + 4 * i) = CF4(src + 4 * i);
  }
  const int r0 = (t >> 3) * 2;   // stage-1 rows
  const int j0 = (t & 7) * 4;    // output cols
  const int i2 = t >> 3;         // stage-2 row
  for (int tt = 0; tt < 3; ++tt) {
    const float* W = (tt == 0) ? Wq : ((tt == 1) ? Wk : Wv);
    __syncthreads();  // protect Wsh/Ts from previous type (also covers Xs @ tt=0)
    F4(&Wsh[t * 8]) = CF4(W + t * 8);
    F4(&Wsh[t * 8 + 4]) = CF4(W + t * 8 + 4);
    __syncthreads();
    // stage 1: T = X * W   (64x32)
    float a0[4] = {0.f, 0.f, 0.f, 0.f}, a1[4] = {0.f, 0.f, 0.f, 0.f};
    for (int k = 0; k < 64; ++k) {
      const float x0 = Xs[r0 * 68 + k];
      const float x1 = Xs[(r0 + 1) * 68 + k];
      const float4 w = CF4(&Wsh[k * 32 + j0]);
      a0[0] += x0 * w.x; a0[1] += x0 * w.y; a0[2] += x0 * w.z; a0[3] += x0 * w.w;
      a1[0] += x1 * w.x; a1[1] += x1 * w.y; a1[2] += x1 * w.z; a1[3] += x1 * w.w;
    }
    F4(&Ts[r0 * 36 + j0])       = make_float4(a0[0], a0[1], a0[2], a0[3]);
    F4(&Ts[(r0 + 1) * 36 + j0]) = make_float4(a1[0], a1[1], a1[2], a1[3]);
    __syncthreads();
    // stage 2: P = W^T * T  (32x32)
    float b4[4] = {0.f, 0.f, 0.f, 0.f};
    for (int p = 0; p < 64; ++p) {
      const float wv = Wsh[p * 32 + i2];
      const float4 tv = CF4(&Ts[p * 36 + j0]);
      b4[0] += wv * tv.x; b4[1] += wv * tv.y; b4[2] += wv * tv.z; b4[3] += wv * tv.w;
    }
    F4(&P[((size_t)tt * kNMAT + bm) * kMSZ + i2 * 32 + j0]) =
        make_float4(b4[0], b4[1], b4[2], b4[3]);
  }
}

// ----------------------------------------------------- one-sided Jacobi ----
// Register-resident Brent-Luk one-sided Jacobi. 4 waves/block, one matrix per
// wave. All 32 columns live in REGISTERS: lane layout g=lane&15 (pair group),
// sub=lane>>4 (row quarter, 8 floats per lane per column). Per round:
//   - apq dot: 8 FMA + cross-sub reduce (shfl_xor 16/32; LDS pipe is idle)
//   - rotation + column update: pure VALU
//   - Brent-Luk ring exchange: p-cols flow from group g+1 (DPP row_ror:15),
//     q-cols from group g-1 (DPP row_ror:1); boundary groups via cndmask.
//     Column norms flow alongside as registers (analytic rotation update).
// After 31 exchanges the ring returns to the initial assignment, so after any
// whole number of sweeps group g holds its initial columns (p0,q0).
// LDS used only once at the end: write columns, exact-norm epilogue,
// log A = B diag(log sigma / sigma^2) B^T.
constexpr int kJSlot = 32 * 36 + 32;  // 1152 col data + 32 norms = 1184 floats

template <int CTRL>
__device__ __forceinline__ float dppf(float x) {
  return __builtin_bit_cast(float,
      __builtin_amdgcn_update_dpp(__builtin_bit_cast(int, x),
                                  __builtin_bit_cast(int, x),
                                  CTRL, 0xf, 0xf, true));
}
// row_ror:1  (0x121): lane i <- lane (i-1)&15  (value from group g-1)
// row_ror:15 (0x12F): lane i <- lane (i+1)&15  (value from group g+1)
constexpr int kRorFromPrev = 0x121;
constexpr int kRorFromNext = 0x12F;

__global__ __launch_bounds__(256, 4) void k_jacobi_log(float* __restrict__ P,
                                                       float* __restrict__ sq) {
  __shared__ float lds[4 * kJSlot];
  const int t = threadIdx.x;
  const int wid = t >> 6, lane = t & 63;
  const int g = lane & 15;         // pair group
  const int sub = lane >> 4;       // row quarter
  const int off = sub * 8;
  const size_t gid = (size_t)blockIdx.x * 4 + wid;  // type*4096 + bm
  float* A = P + gid * kMSZ;
  float* Bs = lds + wid * kJSlot;
  float* ncol = Bs + 1152;  // reused as wcol in the epilogue

  const bool is_g0 = (g == 0);
  const bool is_g15 = (g == 15);
  // initial columns: g==0 -> {31, 0}; else {g, 31-g}
  const int p0 = is_g0 ? 31 : g;
  const int q0 = is_g0 ? 0 : 31 - g;

  float cp[8], cq[8];
  {  // A is symmetric: column c == row c (row-major, 32 floats, 128B aligned)
    const float* pr = A + p0 * 32 + off;
    const float* qr = A + q0 * 32 + off;
    float4 v;
    v = CF4(pr);     cp[0]=v.x; cp[1]=v.y; cp[2]=v.z; cp[3]=v.w;
    v = CF4(pr + 4); cp[4]=v.x; cp[5]=v.y; cp[6]=v.z; cp[7]=v.w;
    v = CF4(qr);     cq[0]=v.x; cq[1]=v.y; cq[2]=v.z; cq[3]=v.w;
    v = CF4(qr + 4); cq[4]=v.x; cq[5]=v.y; cq[6]=v.z; cq[7]=v.w;
  }
  // initial squared norms (reduce across the 4 subs: lanes l, l^16, l^32, l^48)
  float app = 0.f, aqq = 0.f;
#pragma unroll
  for (int i = 0; i < 8; ++i) {
    app = fmaf(cp[i], cp[i], app);
    aqq = fmaf(cq[i], cq[i], aqq);
  }
  app += __shfl_xor(app, 16); app += __shfl_xor(app, 32);
  aqq += __shfl_xor(aqq, 16); aqq += __shfl_xor(aqq, 32);

  for (int sw = 0; sw < kNSweep; ++sw) {
    for (int r = 0; r < 31; ++r) {
      // apq = colp . colq (two FMA chains for ILP, then cross-sub reduce)
      float d0 = cp[0] * cq[0], d1 = cp[1] * cq[1];
#pragma unroll
      for (int i = 2; i < 8; i += 2) {
        d0 = fmaf(cp[i], cq[i], d0);
        d1 = fmaf(cp[i + 1], cq[i + 1], d1);
      }
      float apq = d0 + d1;
      apq += __shfl_xor(apq, 16);
      apq += __shfl_xor(apq, 32);
      // branchless Jacobi rotation (guarded against 0/0)
      float denom = 2.f * apq;
      denom = (denom == 0.f) ? 1e-30f : denom;
      const float tau = (aqq - app) * __builtin_amdgcn_rcpf(denom);
      const float tt = copysignf(1.f, tau) *
          __builtin_amdgcn_rcpf(fabsf(tau) + __builtin_amdgcn_sqrtf(fmaf(tau, tau, 1.f)));
      const float c = __builtin_amdgcn_rsqf(fmaf(tt, tt, 1.f));
      const float sn = tt * c;
      float np[8], nq[8];
#pragma unroll
      for (int i = 0; i < 8; ++i) {
        np[i] = fmaf(c, cp[i], -sn * cq[i]);
        nq[i] = fmaf(sn, cp[i], c * cq[i]);
      }
      // analytic norm update (rotation preserves app+aqq; np.nq == 0)
      const float cs = c * sn;
      float capp = fmaf(c * c, app, fmaf(sn * sn, aqq, -2.f * cs * apq));
      float caqq = (app + aqq) - capp;
      // Brent-Luk ring exchange:
      //   new_p[g] = g==0 ? np : (g==15 ? nq : np from g+1)
      //   new_q[g] = g==0 ? (np from g+1) : (nq from g-1)
#pragma unroll
      for (int i = 0; i < 8; ++i) {
        const float pin = dppf<kRorFromNext>(np[i]);
        const float qin = dppf<kRorFromPrev>(nq[i]);
        const float pm = is_g15 ? nq[i] : pin;
        cp[i] = is_g0 ? np[i] : pm;
        cq[i] = is_g0 ? pin : qin;
      }
      {
        const float apin = dppf<kRorFromNext>(capp);
        const float aqin = dppf<kRorFromPrev>(caqq);
        const float am = is_g15 ? caqq : apin;
        app = is_g0 ? capp : am;
        aqq = is_g0 ? apin : aqin;
      }
    }
  }
  // write final columns to LDS (column-major, stride 36 floats = 144B, 16B-aligned)
  F4(&Bs[p0 * 36 + off])     = make_float4(cp[0], cp[1], cp[2], cp[3]);
  F4(&Bs[p0 * 36 + off + 4]) = make_float4(cp[4], cp[5], cp[6], cp[7]);
  F4(&Bs[q0 * 36 + off])     = make_float4(cq[0], cq[1], cq[2], cq[3]);
  F4(&Bs[q0 * 36 + off + 4]) = make_float4(cq[4], cq[5], cq[6], cq[7]);
  __builtin_amdgcn_wave_barrier();
  {  // exact column norms -> sigma^2; w_c = log(sigma)/sigma^2; sumsq
    const int cc_ = lane & 31, h = lane >> 5;
    const float* col = &Bs[cc_ * 36 + h * 16];
    float ssum = 0.f;
#pragma unroll
    for (int i = 0; i < 16; i += 4) {
      const float4 v = CF4(col + i);
      ssum += v.x * v.x + v.y * v.y + v.z * v.z + v.w * v.w;
    }
    ssum += __shfl_xor(ssum, 32);
    const float lg = 0.5f * logf(ssum);  // log sigma_c
    float tot = lg * lg;
    tot += __shfl_xor(tot, 1);  tot += __shfl_xor(tot, 2);
    tot += __shfl_xor(tot, 4);  tot += __shfl_xor(tot, 8);
    tot += __shfl_xor(tot, 16); tot += __shfl_xor(tot, 32);
    if (lane == 0) sq[gid] = 0.5f * tot;  // each column counted twice
    if (h == 0) ncol[cc_] = lg / ssum;
  }
  __builtin_amdgcn_wave_barrier();
  {  // log A = B diag(w) B^T, 4x4 tile per lane, write back to global (row-major)
    const int rr = (lane >> 3) * 4, cc = (lane & 7) * 4;
    float acc[4][4] = {};
    for (int c = 0; c < 32; ++c) {
      const float w = ncol[c];
      const float4 br = CF4(&Bs[c * 36 + rr]);
      const float4 bc = CF4(&Bs[c * 36 + cc]);
      const float wr[4]  = {w * br.x, w * br.y, w * br.z, w * br.w};
      const float bcv[4] = {bc.x, bc.y, bc.z, bc.w};
#pragma unroll
      for (int i = 0; i < 4; ++i)
#pragma unroll
        for (int j2 = 0; j2 < 4; ++j2) acc[i][j2] += wr[i] * bcv[j2];
    }
#pragma unroll
    for (int i = 0; i < 4; ++i)
      F4(&A[(rr + i) * 32 + cc]) =
          make_float4(acc[i][0], acc[i][1], acc[i][2], acc[i][3]);
  }
}

// ------------------------------------------------- scores/softmax/attn ----
// Block: (jt, b); computes scores[i=0..127][j in 32-wide tile], softmax over i,
// writes attn[b][j][i].
__global__ __launch_bounds__(256) void k_attn(
    const float* __restrict__ P, const float* __restrict__ sq,
    float* __restrict__ attn) {
  __shared__ float Ks[128 * 36];  // logK chunk, later reused for scores
  __shared__ float Qs[32 * 36];
  __shared__ float red[8 * 36];
  __shared__ float mcol[32];
  __shared__ float scol[32];
  const int t = threadIdx.x;
  const int b = blockIdx.y, jt = blockIdx.x;
  const int j0g = jt * 32;
  const float* logK = P + ((size_t)kNMAT + (size_t)b * kM) * kMSZ;
  const float* logQ = P + ((size_t)b * kM + j0g) * kMSZ;
  const int i0 = (t >> 3) * 4, j0 = (t & 7) * 4;
  float acc[4][4] = {};
  for (int dc = 0; dc < kMSZ; dc += 32) {
    __syncthreads();
    {  // stage logK rows 0..127, cols dc..dc+31
      const int r = t >> 1, c0 = (t & 1) * 16;
      const float* src = logK + (size_t)r * kMSZ + dc + c0;
      float* dst = &Ks[r * 36 + c0];
#pragma unroll
      for (int i = 0; i < 4; ++i) F4(dst + 4 * i) = CF4(src + 4 * i);
    }
    {  // stage logQ tile rows
      const int r = t >> 3, c0 = (t & 7) * 4;
      F4(&Qs[r * 36 + c0]) = CF4(logQ + (size_t)r * kMSZ + dc + c0);
    }
    __syncthreads();
    for (int k = 0; k < 32; ++k) {
      float kv[4], qv[4];
#pragma unroll
      for (int i = 0; i < 4; ++i) kv[i] = Ks[(i0 + i) * 36 + k];
#pragma unroll
      for (int j2 = 0; j2 < 4; ++j2) qv[j2] = Qs[(j0 + j2) * 36 + k];
#pragma unroll
      for (int i = 0; i < 4; ++i)
#pragma unroll
        for (int j2 = 0; j2 < 4; ++j2) acc[i][j2] += kv[i] * qv[j2];
    }
  }
  __syncthreads();
  {  // energy -> scores, into Ks[i][jl]
    float k2v[4], q2v[4];
#pragma unroll
    for (int i = 0; i < 4; ++i) k2v[i] = sq[kNMAT + b * kM + i0 + i];
#pragma unroll
    for (int j2 = 0; j2 < 4; ++j2) q2v[j2] = sq[b * kM + j0g + j0 + j2];
#pragma unroll
    for (int i = 0; i < 4; ++i)
#pragma unroll
      for (int j2 = 0; j2 < 4; ++j2) {
        float e = k2v[i] + q2v[j2] - 2.f * acc[i][j2];
        e = fmaxf(e, 0.f);
        Ks[(i0 + i) * 36 + (j0 + j2)] = 1.f / (1.f + log1pf(e));
      }
  }
  __syncthreads();
  const int jl = t & 31, grp = t >> 5;
  {
    float m = -1e30f;
    for (int i = grp * 16; i < grp * 16 + 16; ++i) m = fmaxf(m, Ks[i * 36 + jl]);
    red[grp * 36 + jl] = m;
  }
  __syncthreads();
  if (t < 32) {
    float m = red[t];
#pragma unroll
    for (int g = 1; g < 8; ++g) m = fmaxf(m, red[g * 36 + t]);
    mcol[t] = m;
  }
  __syncthreads();
  {
    const float mj = mcol[jl];
    float s = 0.f;
    for (int i = grp * 16; i < grp * 16 + 16; ++i) s += expf(Ks[i * 36 + jl] - mj);
    red[grp * 36 + jl] = s;
  }
  __syncthreads();
  if (t < 32) {
    float s = red[t];
#pragma unroll
    for (int g = 1; g < 8; ++g) s += red[g * 36 + t];
    scol[t] = 1.f / s;
  }
  __syncthreads();
  {  // write attn[b][j][i], coalesced in i
    const int il = t & 31, jg = t >> 5;
#pragma unroll
    for (int rep = 0; rep < 4; ++rep) {
      const int j2 = jg + rep * 8;
      const float mj = mcol[j2], is = scol[j2];
      float* dst = attn + ((size_t)b * kM + j0g + j2) * kM;
#pragma unroll
      for (int c4 = 0; c4 < 4; ++c4) {
        const int i = il + c4 * 32;
        dst[i] = expf(Ks[i * 36 + j2] - mj) * is;
      }
    }
  }
}

// -------------------------------------------------------------- meanlog ----
// ML[b][j][:] = sum_i attn[b][j][i] * logV[b][i][:]   (GEMM 32x1024, K=128)
__global__ __launch_bounds__(256) void k_meanlog(
    const float* __restrict__ attn, const float* __restrict__ P,
    float* __restrict__ ML) {
  __shared__ float As[32 * 132];
  __shared__ float Vs[128 * 64];
  const int t = threadIdx.x;
  const int b = blockIdx.y, jt = blockIdx.x;
  const int j0g = jt * 32;
  const float* logV = P + ((size_t)2 * kNMAT + (size_t)b * kM) * kMSZ;
  {  // stage attn tile [32][128]
    const int r = t >> 3, c0 = (t & 7) * 16;
    const float* src = attn + ((size_t)b * kM + j0g + r) * kM + c0;
    float* dst = &As[r * 132 + c0];
#pragma unroll
    for (int i = 0; i < 4; ++i) F4(dst + 4 * i) = CF4(src + 4 * i);
  }
  const int j0 = (t >> 4) * 2, d0 = (t & 15) * 4;
  for (int dc = 0; dc < kMSZ; dc += 64) {
    __syncthreads();
    {  // stage logV[k=0..127][dc..dc+63]
      const int r = t >> 1, c0 = (t & 1) * 32;
      const float* src = logV + (size_t)r * kMSZ + dc + c0;
      float* dst = &Vs[r * 64 + c0];
#pragma unroll
      for (int i = 0; i < 8; ++i) F4(dst + 4 * i) = CF4(src + 4 * i);
    }
    __syncthreads();
    float a0[4] = {0.f,0.f,0.f,0.f}, a1[4] = {0.f,0.f,0.f,0.f};
    for (int k = 0; k < kM; ++k) {
      const float w0 = As[(j0 + 0) * 132 + k];
      const float w1 = As[(j0 + 1) * 132 + k];
      const float4 v = CF4(&Vs[k * 64 + d0]);
      a0[0] += w0 * v.x; a0[1] += w0 * v.y; a0[2] += w0 * v.z; a0[3] += w0 * v.w;
      a1[0] += w1 * v.x; a1[1] += w1 * v.y; a1[2] += w1 * v.z; a1[3] += w1 * v.w;
    }
    F4(&ML[((size_t)b * kM + j0g + j0 + 0) * kMSZ + dc + d0]) =
        make_float4(a0[0], a0[1], a0[2], a0[3]);
    F4(&ML[((size_t)b * kM + j0g + j0 + 1) * kMSZ + dc + d0]) =
        make_float4(a1[0], a1[1], a1[2], a1[3]);
  }
}

// ------------------------------------------------------------------ exp ----
// out = exp(S): scaling-and-squaring + degree-10 Horner Taylor. One wave per matrix.
__global__ __launch_bounds__(64) void k_expm(const float* __restrict__ ML,
                                             float* __restrict__ out) {
  __shared__ float Mb[32 * 36];
  __shared__ float Tb[2][32 * 36];
  const int lane = threadIdx.x;
  const size_t bm = blockIdx.x;
  const float* S = ML + bm * kMSZ;
  const int r = lane >> 1, c0 = (lane & 1) * 16;
  float lsum = 0.f;
#pragma unroll
  for (int i = 0; i < 16; i += 4) {
    const float4 v = CF4(S + r * 32 + c0 + i);
    F4(&Mb[r * 36 + c0 + i]) = v;
    lsum += v.x * v.x + v.y * v.y + v.z * v.z + v.w * v.w;
  }
#pragma unroll
  for (int d = 1; d < 64; d <<= 1) lsum += __shfl_xor(lsum, d);
  const float fn = sqrtf(lsum);     // Frobenius norm >= spectral norm
  int sc = 0;
  if (fn > 0.5f) sc = (int)ceilf(log2f(fn * 2.0f));
  const float scale = exp2f((float)(-sc));
  __syncthreads();
#pragma unroll
  for (int i = 0; i < 16; i += 4) {
    float4 v = F4(&Mb[r * 36 + c0 + i]);
    v.x *= scale; v.y *= scale; v.z *= scale; v.w *= scale;
    F4(&Mb[r * 36 + c0 + i]) = v;
  }
  __syncthreads();
  const int rr = (lane >> 3) * 4, cc = (lane & 7) * 4;
#pragma unroll
  for (int i = 0; i < 4; ++i) {  // T = I + M/10
    float4 v = F4(&Mb[(rr + i) * 36 + cc]);
    v.x = v.x * 0.1f + ((rr + i == cc + 0) ? 1.f : 0.f);
    v.y = v.y * 0.1f + ((rr + i == cc + 1) ? 1.f : 0.f);
    v.z = v.z * 0.1f + ((rr + i == cc + 2) ? 1.f : 0.f);
    v.w = v.w * 0.1f + ((rr + i == cc + 3) ? 1.f : 0.f);
    F4(&Tb[0][(rr + i) * 36 + cc]) = v;
  }
  __syncthreads();
  int cur = 0;
  for (int j = 9; j >= 1; --j) {  // T <- I + (M*T)/j
    float a4[4][4] = {};
    for (int k = 0; k < 32; ++k) {
      float mv[4];
#pragma unroll
      for (int i = 0; i < 4; ++i) mv[i] = Mb[(rr + i) * 36 + k];
      const float4 tv = CF4(&Tb[cur][k * 36 + cc]);
      const float tvv[4] = {tv.x, tv.y, tv.z, tv.w};
#pragma unroll
      for (int i = 0; i < 4; ++i)
#pragma unroll
        for (int j2 = 0; j2 < 4; ++j2) a4[i][j2] += mv[i] * tvv[j2];
    }
    const float inv = 1.f / (float)j;
#pragma unroll
    for (int i = 0; i < 4; ++i) {
      float4 v;
      v.x = a4[i][0] * inv + ((rr + i == cc + 0) ? 1.f : 0.f);
      v.y = a4[i][1] * inv + ((rr + i == cc + 1) ? 1.f : 0.f);
      v.z = a4[i][2] * inv + ((rr + i == cc + 2) ? 1.f : 0.f);
      v.w = a4[i][3] * inv + ((rr + i == cc + 3) ? 1.f : 0.f);
      F4(&Tb[cur ^ 1][(rr + i) * 36 + cc]) = v;
    }
    __syncthreads();
    cur ^= 1;
  }
  for (int st = 0; st < sc; ++st) {  // T <- T*T
    float a4[4][4] = {};
    for (int k = 0; k < 32; ++k) {
      float mv[4];
#pragma unroll
      for (int i = 0; i < 4; ++i) mv[i] = Tb[cur][(rr + i) * 36 + k];
      const float4 tv = CF4(&Tb[cur][k * 36 + cc]);
      const float tvv[4] = {tv.x, tv.y, tv.z, tv.w};
#pragma unroll
      for (int i = 0; i < 4; ++i)
#pragma unroll
        for (int j2 = 0; j2 < 4; ++j2) a4[i][j2] += mv[i] * tvv[j2];
    }
#pragma unroll
    for (int i = 0; i < 4; ++i)
      F4(&Tb[cur ^ 1][(rr + i) * 36 + cc]) =
          make_float4(a4[i][0], a4[i][1], a4[i][2], a4[i][3]);
    __syncthreads();
    cur ^= 1;
  }
#pragma unroll
  for (int i = 0; i < 4; ++i) {
    const float4 v = CF4(&Tb[cur][(rr + i) * 36 + cc]);
    F4(&out[bm * kMSZ + (rr + i) * 32 + cc]) = v;
  }
}

// -------------------------------------------------------------- launch ----
extern "C" void kernel_launch(void* const* d_in, const int* in_sizes, int n_in,
                              void* d_out, int out_size, void* d_ws, size_t ws_size,
                              hipStream_t stream) {
  const float* x  = (const float*)d_in[0];
  const float* Wq = (const float*)d_in[1];
  const float* Wk = (const float*)d_in[2];
  const float* Wv = (const float*)d_in[3];
  float* ws   = (float*)d_ws;
  float* P    = ws;                 // [3][4096][1024]
  float* sq   = ws + OFF_SS;        // [3][4096]
  float* attn = ws + OFF_ATTN;      // [32][128][128]
  float* ML   = ws;                 // reuse logQ region (dead after k_attn)
  float* out  = (float*)d_out;

  k_bimap<<<kNMAT, 256, 0, stream>>>(x, Wq, Wk, Wv, P);
  k_jacobi_log<<<3 * kNMAT / 4, 256, 0, stream>>>(P, sq);
  k_attn<<<dim3(4, kBS), 256, 0, stream>>>(P, sq, attn);
  k_meanlog<<<dim3(4, kBS), 256, 0, stream>>>(attn, P, ML);
  k_expm<<<kNMAT, 64, 0, stream>>>(ML, out);
}

// Round 4
// 602.222 us; speedup vs baseline: 1.7629x; 1.3481x over previous
//
#include <hip/hip_runtime.h>
#include <math.h>

// Problem constants
constexpr int kBS = 32, kM = 128, kNMAT = kBS * kM;         // 4096 (b,m) pairs
constexpr int kDIN = 64, kDOUT = 32, kMSZ = kDOUT * kDOUT;  // 1024 floats per 32x32
constexpr int kNSweep = 6;                                  // Jacobi sweeps (8->6: off-norm ~1e-7, 4x absmax margin)

// ws layout (floats):
//   P/log : [3][4096][1024]  (Q=0,K=1,V=2; overwritten in place by logs)
//   sumsq : [3][4096]        (||log||_F^2 per matrix)
//   attn  : [32][128][128]
// mean_log reuses the logQ region (dead after k_attn).
constexpr size_t OFF_SS   = (size_t)3 * kNMAT * kMSZ;
constexpr size_t OFF_ATTN = OFF_SS + (size_t)3 * kNMAT;

#define F4(p)  (*(float4*)(p))
#define CF4(p) (*(const float4*)(p))

// ---------------------------------------------------------------- bimap ----
// P_t = W_t^T X W_t for t in {Q,K,V}; one block per (b,m).
__global__ __launch_bounds__(256) void k_bimap(
    const float* __restrict__ x, const float* __restrict__ Wq,
    const float* __restrict__ Wk, const float* __restrict__ Wv,
    float* __restrict__ P) {
  __shared__ float Xs[64 * 68];   // X, row-major padded
  __shared__ float Wsh[64 * 32];  // current W, row-major
  __shared__ float Ts[64 * 36];   // T = X*W, padded
  const int t = threadIdx.x;
  const int bm = blockIdx.x;
  const float* xp = x + (size_t)bm * (kDIN * kDIN);
  {
    const int f0 = t * 16;
    const int r = f0 >> 6, c = f0 & 63;
    const float* src = xp + f0;
    float* dst = &Xs[r * 68 + c];
#pragma unroll
    for (int i = 0; i < 4; ++i) F4(dst + 4 * i) = CF4(src + 4 * i);
  }
  const int r0 = (t >> 3) * 2;   // stage-1 rows
  const int j0 = (t & 7) * 4;    // output cols
  const int i2 = t >> 3;         // stage-2 row
  for (int tt = 0; tt < 3; ++tt) {
    const float* W = (tt == 0) ? Wq : ((tt == 1) ? Wk : Wv);
    __syncthreads();  // protect Wsh/Ts from previous type (also covers Xs @ tt=0)
    F4(&Wsh[t * 8]) = CF4(W + t * 8);
    F4(&Wsh[t * 8 + 4]) = CF4(W + t * 8 + 4);
    __syncthreads();
    // stage 1: T = X * W   (64x32)
    float a0[4] = {0.f, 0.f, 0.f, 0.f}, a1[4] = {0.f, 0.f, 0.f, 0.f};
    for (int k = 0; k < 64; ++k) {
      const float x0 = Xs[r0 * 68 + k];
      const float x1 = Xs[(r0 + 1) * 68 + k];
      const float4 w = CF4(&Wsh[k * 32 + j0]);
      a0[0] += x0 * w.x; a0[1] += x0 * w.y; a0[2] += x0 * w.z; a0[3] += x0 * w.w;
      a1[0] += x1 * w.x; a1[1] += x1 * w.y; a1[2] += x1 * w.z; a1[3] += x1 * w.w;
    }
    F4(&Ts[r0 * 36 + j0])       = make_float4(a0[0], a0[1], a0[2], a0[3]);
    F4(&Ts[(r0 + 1) * 36 + j0]) = make_float4(a1[0], a1[1], a1[2], a1[3]);
    __syncthreads();
    // stage 2: P = W^T * T  (32x32)
    float b4[4] = {0.f, 0.f, 0.f, 0.f};
    for (int p = 0; p < 64; ++p) {
      const float wv = Wsh[p * 32 + i2];
      const float4 tv = CF4(&Ts[p * 36 + j0]);
      b4[0] += wv * tv.x; b4[1] += wv * tv.y; b4[2] += wv * tv.z; b4[3] += wv * tv.w;
    }
    F4(&P[((size_t)tt * kNMAT + bm) * kMSZ + i2 * 32 + j0]) =
        make_float4(b4[0], b4[1], b4[2], b4[3]);
  }
}

// ----------------------------------------------------- one-sided Jacobi ----
// Register-resident Brent-Luk one-sided Jacobi. 4 waves/block, one matrix per
// wave. Lane layout: g=lane&15 (pair group), sub=lane>>4 (row quarter).
// Ring exchange via update_dpp row_shl:1 / row_shr:1 with bound_ctrl=off:
// the out-of-range lane keeps `old`, which IS the tournament boundary value,
// so each element-pair exchange is {copy+dpp, cndmask, dpp} = 4 instrs.
//   cpm = update_dpp(old=nq, src=np, row_shl:1) : g<=14 -> np[g+1], g15 -> nq
//   cp  = g==0 ? np : cpm
//   cq  = update_dpp(old=cpm, src=nq, row_shr:1): g>=1 -> nq[g-1], g0 -> np[1]
constexpr int kJSlot = 32 * 36 + 32;  // 1152 col data + 32 norms = 1184 floats
constexpr int kShl1 = 0x101, kShr1 = 0x111;

template <int CTRL>
__device__ __forceinline__ float updppf(float old_, float x) {
  return __builtin_bit_cast(float,
      __builtin_amdgcn_update_dpp(__builtin_bit_cast(int, old_),
                                  __builtin_bit_cast(int, x),
                                  CTRL, 0xf, 0xf, false));
}

__global__ __launch_bounds__(256, 4) void k_jacobi_log(float* __restrict__ P,
                                                       float* __restrict__ sq) {
  __shared__ float lds[4 * kJSlot];
  const int t = threadIdx.x;
  const int wid = t >> 6, lane = t & 63;
  const int g = lane & 15;         // pair group
  const int sub = lane >> 4;       // row quarter
  const int off = sub * 8;
  const size_t gid = (size_t)blockIdx.x * 4 + wid;  // type*4096 + bm
  float* A = P + gid * kMSZ;
  float* Bs = lds + wid * kJSlot;
  float* ncol = Bs + 1152;  // reused as wcol in the epilogue

  const bool is_g0 = (g == 0);
  // initial columns: g==0 -> {31, 0}; else {g, 31-g}
  const int p0 = is_g0 ? 31 : g;
  const int q0 = is_g0 ? 0 : 31 - g;

  float cp[8], cq[8];
  {  // A is symmetric: column c == row c (row-major, 32 floats, 128B aligned)
    const float* pr = A + p0 * 32 + off;
    const float* qr = A + q0 * 32 + off;
    float4 v;
    v = CF4(pr);     cp[0]=v.x; cp[1]=v.y; cp[2]=v.z; cp[3]=v.w;
    v = CF4(pr + 4); cp[4]=v.x; cp[5]=v.y; cp[6]=v.z; cp[7]=v.w;
    v = CF4(qr);     cq[0]=v.x; cq[1]=v.y; cq[2]=v.z; cq[3]=v.w;
    v = CF4(qr + 4); cq[4]=v.x; cq[5]=v.y; cq[6]=v.z; cq[7]=v.w;
  }
  // initial squared norms (reduce across the 4 subs: lanes l, l^16, l^32, l^48)
  float app = 0.f, aqq = 0.f;
#pragma unroll
  for (int i = 0; i < 8; ++i) {
    app = fmaf(cp[i], cp[i], app);
    aqq = fmaf(cq[i], cq[i], aqq);
  }
  app += __shfl_xor(app, 16); app += __shfl_xor(app, 32);
  aqq += __shfl_xor(aqq, 16); aqq += __shfl_xor(aqq, 32);

  for (int sw = 0; sw < kNSweep; ++sw) {
    for (int r = 0; r < 31; ++r) {
      // apq = colp . colq (two FMA chains for ILP, then cross-sub reduce)
      float d0 = cp[0] * cq[0], d1 = cp[1] * cq[1];
#pragma unroll
      for (int i = 2; i < 8; i += 2) {
        d0 = fmaf(cp[i], cq[i], d0);
        d1 = fmaf(cp[i + 1], cq[i + 1], d1);
      }
      float apq = d0 + d1;
      apq += __shfl_xor(apq, 16);
      apq += __shfl_xor(apq, 32);
      // branchless Jacobi rotation. Degenerate cases are graceful:
      //   apq==0, aqq!=app -> tau huge -> tt ~ 0 (no-op rotation)
      //   apq==0, aqq==app -> tau=0 -> tt=1 (45deg rotation of an orthogonal
      //     equal-norm pair: harmless for one-sided Jacobi)
      float denom = 2.f * apq;
      denom = (denom == 0.f) ? 1e-30f : denom;
      const float tau = (aqq - app) * __builtin_amdgcn_rcpf(denom);
      const float root = __builtin_amdgcn_sqrtf(fmaf(tau, tau, 1.f));
      const float tt = __builtin_amdgcn_rcpf(tau + copysignf(root, tau));
      const float c = __builtin_amdgcn_rsqf(fmaf(tt, tt, 1.f));
      const float sn = tt * c;
      float np[8], nq[8];
#pragma unroll
      for (int i = 0; i < 8; ++i) {
        const float t1 = c * cp[i];
        const float t2 = sn * cp[i];
        np[i] = fmaf(-sn, cq[i], t1);
        nq[i] = fmaf(c, cq[i], t2);
      }
      // analytic norm update (rotation preserves app+aqq; np.nq == 0)
      const float c2 = c * c, s2 = sn * sn, cs2 = 2.f * c * sn;
      const float capp = fmaf(c2, app, fmaf(s2, aqq, -cs2 * apq));
      const float caqq = (app + aqq) - capp;
      // ring exchange (4 instrs per element pair; see header comment)
#pragma unroll
      for (int i = 0; i < 8; ++i) {
        const float cpm = updppf<kShl1>(nq[i], np[i]);
        cp[i] = is_g0 ? np[i] : cpm;
        cq[i] = updppf<kShr1>(cpm, nq[i]);
      }
      {
        const float capm = updppf<kShl1>(caqq, capp);
        app = is_g0 ? capp : capm;
        aqq = updppf<kShr1>(capm, caqq);
      }
    }
  }
  // write final columns to LDS (column-major, stride 36 floats = 144B, 16B-aligned)
  F4(&Bs[p0 * 36 + off])     = make_float4(cp[0], cp[1], cp[2], cp[3]);
  F4(&Bs[p0 * 36 + off + 4]) = make_float4(cp[4], cp[5], cp[6], cp[7]);
  F4(&Bs[q0 * 36 + off])     = make_float4(cq[0], cq[1], cq[2], cq[3]);
  F4(&Bs[q0 * 36 + off + 4]) = make_float4(cq[4], cq[5], cq[6], cq[7]);
  __builtin_amdgcn_wave_barrier();
  {  // exact column norms -> sigma^2; w_c = log(sigma)/sigma^2; sumsq
    const int cc_ = lane & 31, h = lane >> 5;
    const float* col = &Bs[cc_ * 36 + h * 16];
    float ssum = 0.f;
#pragma unroll
    for (int i = 0; i < 16; i += 4) {
      const float4 v = CF4(col + i);
      ssum += v.x * v.x + v.y * v.y + v.z * v.z + v.w * v.w;
    }
    ssum += __shfl_xor(ssum, 32);
    const float lg = 0.5f * logf(ssum);  // log sigma_c
    float tot = lg * lg;
    tot += __shfl_xor(tot, 1);  tot += __shfl_xor(tot, 2);
    tot += __shfl_xor(tot, 4);  tot += __shfl_xor(tot, 8);
    tot += __shfl_xor(tot, 16); tot += __shfl_xor(tot, 32);
    if (lane == 0) sq[gid] = 0.5f * tot;  // each column counted twice
    if (h == 0) ncol[cc_] = lg / ssum;
  }
  __builtin_amdgcn_wave_barrier();
  {  // log A = B diag(w) B^T, 4x4 tile per lane, write back to global (row-major)
    const int rr = (lane >> 3) * 4, cc = (lane & 7) * 4;
    float acc[4][4] = {};
    for (int c = 0; c < 32; ++c) {
      const float w = ncol[c];
      const float4 br = CF4(&Bs[c * 36 + rr]);
      const float4 bc = CF4(&Bs[c * 36 + cc]);
      const float wr[4]  = {w * br.x, w * br.y, w * br.z, w * br.w};
      const float bcv[4] = {bc.x, bc.y, bc.z, bc.w};
#pragma unroll
      for (int i = 0; i < 4; ++i)
#pragma unroll
        for (int j2 = 0; j2 < 4; ++j2) acc[i][j2] += wr[i] * bcv[j2];
    }
#pragma unroll
    for (int i = 0; i < 4; ++i)
      F4(&A[(rr + i) * 32 + cc]) =
          make_float4(acc[i][0], acc[i][1], acc[i][2], acc[i][3]);
  }
}

// ------------------------------------------------- scores/softmax/attn ----
// Block: (jt, b); computes scores[i=0..127][j in 32-wide tile], softmax over i,
// writes attn[b][j][i].
__global__ __launch_bounds__(256) void k_attn(
    const float* __restrict__ P, const float* __restrict__ sq,
    float* __restrict__ attn) {
  __shared__ float Ks[128 * 36];  // logK chunk, later reused for scores
  __shared__ float Qs[32 * 36];
  __shared__ float red[8 * 36];
  __shared__ float mcol[32];
  __shared__ float scol[32];
  const int t = threadIdx.x;
  const int b = blockIdx.y, jt = blockIdx.x;
  const int j0g = jt * 32;
  const float* logK = P + ((size_t)kNMAT + (size_t)b * kM) * kMSZ;
  const float* logQ = P + ((size_t)b * kM + j0g) * kMSZ;
  const int i0 = (t >> 3) * 4, j0 = (t & 7) * 4;
  float acc[4][4] = {};
  for (int dc = 0; dc < kMSZ; dc += 32) {
    __syncthreads();
    {  // stage logK rows 0..127, cols dc..dc+31
      const int r = t >> 1, c0 = (t & 1) * 16;
      const float* src = logK + (size_t)r * kMSZ + dc + c0;
      float* dst = &Ks[r * 36 + c0];
#pragma unroll
      for (int i = 0; i < 4; ++i) F4(dst + 4 * i) = CF4(src + 4 * i);
    }
    {  // stage logQ tile rows
      const int r = t >> 3, c0 = (t & 7) * 4;
      F4(&Qs[r * 36 + c0]) = CF4(logQ + (size_t)r * kMSZ + dc + c0);
    }
    __syncthreads();
    for (int k = 0; k < 32; ++k) {
      float kv[4], qv[4];
#pragma unroll
      for (int i = 0; i < 4; ++i) kv[i] = Ks[(i0 + i) * 36 + k];
#pragma unroll
      for (int j2 = 0; j2 < 4; ++j2) qv[j2] = Qs[(j0 + j2) * 36 + k];
#pragma unroll
      for (int i = 0; i < 4; ++i)
#pragma unroll
        for (int j2 = 0; j2 < 4; ++j2) acc[i][j2] += kv[i] * qv[j2];
    }
  }
  __syncthreads();
  {  // energy -> scores, into Ks[i][jl]
    float k2v[4], q2v[4];
#pragma unroll
    for (int i = 0; i < 4; ++i) k2v[i] = sq[kNMAT + b * kM + i0 + i];
#pragma unroll
    for (int j2 = 0; j2 < 4; ++j2) q2v[j2] = sq[b * kM + j0g + j0 + j2];
#pragma unroll
    for (int i = 0; i < 4; ++i)
#pragma unroll
      for (int j2 = 0; j2 < 4; ++j2) {
        float e = k2v[i] + q2v[j2] - 2.f * acc[i][j2];
        e = fmaxf(e, 0.f);
        Ks[(i0 + i) * 36 + (j0 + j2)] = 1.f / (1.f + log1pf(e));
      }
  }
  __syncthreads();
  const int jl = t & 31, grp = t >> 5;
  {
    float m = -1e30f;
    for (int i = grp * 16; i < grp * 16 + 16; ++i) m = fmaxf(m, Ks[i * 36 + jl]);
    red[grp * 36 + jl] = m;
  }
  __syncthreads();
  if (t < 32) {
    float m = red[t];
#pragma unroll
    for (int g = 1; g < 8; ++g) m = fmaxf(m, red[g * 36 + t]);
    mcol[t] = m;
  }
  __syncthreads();
  {
    const float mj = mcol[jl];
    float s = 0.f;
    for (int i = grp * 16; i < grp * 16 + 16; ++i) s += expf(Ks[i * 36 + jl] - mj);
    red[grp * 36 + jl] = s;
  }
  __syncthreads();
  if (t < 32) {
    float s = red[t];
#pragma unroll
    for (int g = 1; g < 8; ++g) s += red[g * 36 + t];
    scol[t] = 1.f / s;
  }
  __syncthreads();
  {  // write attn[b][j][i], coalesced in i
    const int il = t & 31, jg = t >> 5;
#pragma unroll
    for (int rep = 0; rep < 4; ++rep) {
      const int j2 = jg + rep * 8;
      const float mj = mcol[j2], is = scol[j2];
      float* dst = attn + ((size_t)b * kM + j0g + j2) * kM;
#pragma unroll
      for (int c4 = 0; c4 < 4; ++c4) {
        const int i = il + c4 * 32;
        dst[i] = expf(Ks[i * 36 + j2] - mj) * is;
      }
    }
  }
}

// -------------------------------------------------------------- meanlog ----
// ML[b][j][:] = sum_i attn[b][j][i] * logV[b][i][:]   (GEMM 32x1024, K=128)
__global__ __launch_bounds__(256) void k_meanlog(
    const float* __restrict__ attn, const float* __restrict__ P,
    float* __restrict__ ML) {
  __shared__ float As[32 * 132];
  __shared__ float Vs[128 * 64];
  const int t = threadIdx.x;
  const int b = blockIdx.y, jt = blockIdx.x;
  const int j0g = jt * 32;
  const float* logV = P + ((size_t)2 * kNMAT + (size_t)b * kM) * kMSZ;
  {  // stage attn tile [32][128]
    const int r = t >> 3, c0 = (t & 7) * 16;
    const float* src = attn + ((size_t)b * kM + j0g + r) * kM + c0;
    float* dst = &As[r * 132 + c0];
#pragma unroll
    for (int i = 0; i < 4; ++i) F4(dst + 4 * i) = CF4(src + 4 * i);
  }
  const int j0 = (t >> 4) * 2, d0 = (t & 15) * 4;
  for (int dc = 0; dc < kMSZ; dc += 64) {
    __syncthreads();
    {  // stage logV[k=0..127][dc..dc+63]
      const int r = t >> 1, c0 = (t & 1) * 32;
      const float* src = logV + (size_t)r * kMSZ + dc + c0;
      float* dst = &Vs[r * 64 + c0];
#pragma unroll
      for (int i = 0; i < 8; ++i) F4(dst + 4 * i) = CF4(src + 4 * i);
    }
    __syncthreads();
    float a0[4] = {0.f,0.f,0.f,0.f}, a1[4] = {0.f,0.f,0.f,0.f};
    for (int k = 0; k < kM; ++k) {
      const float w0 = As[(j0 + 0) * 132 + k];
      const float w1 = As[(j0 + 1) * 132 + k];
      const float4 v = CF4(&Vs[k * 64 + d0]);
      a0[0] += w0 * v.x; a0[1] += w0 * v.y; a0[2] += w0 * v.z; a0[3] += w0 * v.w;
      a1[0] += w1 * v.x; a1[1] += w1 * v.y; a1[2] += w1 * v.z; a1[3] += w1 * v.w;
    }
    F4(&ML[((size_t)b * kM + j0g + j0 + 0) * kMSZ + dc + d0]) =
        make_float4(a0[0], a0[1], a0[2], a0[3]);
    F4(&ML[((size_t)b * kM + j0g + j0 + 1) * kMSZ + dc + d0]) =
        make_float4(a1[0], a1[1], a1[2], a1[3]);
  }
}

// ------------------------------------------------------------------ exp ----
// out = exp(S): scaling-and-squaring + degree-10 Horner Taylor.
// 4 waves/block, one matrix per wave in a private LDS slot; no s_barrier.
// T updated IN PLACE: within one wave all ds_reads of an iteration precede
// its ds_writes in program order, and the DS unit is in-order per wave.
constexpr int kESlot = 2 * 1152;  // Mb + Tb

__global__ __launch_bounds__(256) void k_expm(const float* __restrict__ ML,
                                              float* __restrict__ out) {
  __shared__ float lds[4 * kESlot];
  const int t = threadIdx.x;
  const int wid = t >> 6, lane = t & 63;
  const size_t bm = (size_t)blockIdx.x * 4 + wid;
  float* Mb = lds + wid * kESlot;
  float* Tb = Mb + 1152;
  const float* S = ML + bm * kMSZ;
  const int r = lane >> 1, c0 = (lane & 1) * 16;
  float4 v0 = CF4(S + r * 32 + c0),     v1 = CF4(S + r * 32 + c0 + 4),
         v2 = CF4(S + r * 32 + c0 + 8), v3 = CF4(S + r * 32 + c0 + 12);
  float lsum = v0.x*v0.x + v0.y*v0.y + v0.z*v0.z + v0.w*v0.w
             + v1.x*v1.x + v1.y*v1.y + v1.z*v1.z + v1.w*v1.w
             + v2.x*v2.x + v2.y*v2.y + v2.z*v2.z + v2.w*v2.w
             + v3.x*v3.x + v3.y*v3.y + v3.z*v3.z + v3.w*v3.w;
#pragma unroll
  for (int d = 1; d < 64; d <<= 1) lsum += __shfl_xor(lsum, d);
  const float fn = sqrtf(lsum);     // Frobenius norm >= spectral norm
  int sc = 0;
  if (fn > 0.5f) sc = (int)ceilf(log2f(fn * 2.0f));
  const float scale = exp2f((float)(-sc));
  v0.x*=scale; v0.y*=scale; v0.z*=scale; v0.w*=scale;
  v1.x*=scale; v1.y*=scale; v1.z*=scale; v1.w*=scale;
  v2.x*=scale; v2.y*=scale; v2.z*=scale; v2.w*=scale;
  v3.x*=scale; v3.y*=scale; v3.z*=scale; v3.w*=scale;
  F4(&Mb[r * 36 + c0])      = v0;
  F4(&Mb[r * 36 + c0 + 4])  = v1;
  F4(&Mb[r * 36 + c0 + 8])  = v2;
  F4(&Mb[r * 36 + c0 + 12]) = v3;
  __builtin_amdgcn_wave_barrier();
  const int rr = (lane >> 3) * 4, cc = (lane & 7) * 4;
#pragma unroll
  for (int i = 0; i < 4; ++i) {  // T = I + M/10
    float4 v = F4(&Mb[(rr + i) * 36 + cc]);
    v.x = v.x * 0.1f + ((rr + i == cc + 0) ? 1.f : 0.f);
    v.y = v.y * 0.1f + ((rr + i == cc + 1) ? 1.f : 0.f);
    v.z = v.z * 0.1f + ((rr + i == cc + 2) ? 1.f : 0.f);
    v.w = v.w * 0.1f + ((rr + i == cc + 3) ? 1.f : 0.f);
    F4(&Tb[(rr + i) * 36 + cc]) = v;
  }
  __builtin_amdgcn_wave_barrier();
  for (int j = 9; j >= 1; --j) {  // T <- I + (M*T)/j, in place
    float a4[4][4] = {};
    for (int k = 0; k < 32; ++k) {
      float mv[4];
#pragma unroll
      for (int i = 0; i < 4; ++i) mv[i] = Mb[(rr + i) * 36 + k];
      const float4 tv = CF4(&Tb[k * 36 + cc]);
      const float tvv[4] = {tv.x, tv.y, tv.z, tv.w};
#pragma unroll
      for (int i = 0; i < 4; ++i)
#pragma unroll
        for (int j2 = 0; j2 < 4; ++j2) a4[i][j2] += mv[i] * tvv[j2];
    }
    const float inv = 1.f / (float)j;
#pragma unroll
    for (int i = 0; i < 4; ++i) {
      float4 v;
      v.x = a4[i][0] * inv + ((rr + i == cc + 0) ? 1.f : 0.f);
      v.y = a4[i][1] * inv + ((rr + i == cc + 1) ? 1.f : 0.f);
      v.z = a4[i][2] * inv + ((rr + i == cc + 2) ? 1.f : 0.f);
      v.w = a4[i][3] * inv + ((rr + i == cc + 3) ? 1.f : 0.f);
      F4(&Tb[(rr + i) * 36 + cc]) = v;
    }
    __builtin_amdgcn_wave_barrier();
  }
  for (int st = 0; st < sc; ++st) {  // T <- T*T, in place (wave-uniform trip count)
    float a4[4][4] = {};
    for (int k = 0; k < 32; ++k) {
      float mv[4];
#pragma unroll
      for (int i = 0; i < 4; ++i) mv[i] = Tb[(rr + i) * 36 + k];
      const float4 tv = CF4(&Tb[k * 36 + cc]);
      const float tvv[4] = {tv.x, tv.y, tv.z, tv.w};
#pragma unroll
      for (int i = 0; i < 4; ++i)
#pragma unroll
        for (int j2 = 0; j2 < 4; ++j2) a4[i][j2] += mv[i] * tvv[j2];
    }
#pragma unroll
    for (int i = 0; i < 4; ++i)
      F4(&Tb[(rr + i) * 36 + cc]) =
          make_float4(a4[i][0], a4[i][1], a4[i][2], a4[i][3]);
    __builtin_amdgcn_wave_barrier();
  }
#pragma unroll
  for (int i = 0; i < 4; ++i) {
    const float4 v = CF4(&Tb[(rr + i) * 36 + cc]);
    F4(&out[bm * kMSZ + (rr + i) * 32 + cc]) = v;
  }
}

// -------------------------------------------------------------- launch ----
extern "C" void kernel_launch(void* const* d_in, const int* in_sizes, int n_in,
                              void* d_out, int out_size, void* d_ws, size_t ws_size,
                              hipStream_t stream) {
  const float* x  = (const float*)d_in[0];
  const float* Wq = (const float*)d_in[1];
  const float* Wk = (const float*)d_in[2];
  const float* Wv = (const float*)d_in[3];
  float* ws   = (float*)d_ws;
  float* P    = ws;                 // [3][4096][1024]
  float* sq   = ws + OFF_SS;        // [3][4096]
  float* attn = ws + OFF_ATTN;      // [32][128][128]
  float* ML   = ws;                 // reuse logQ region (dead after k_attn)
  float* out  = (float*)d_out;

  k_bimap<<<kNMAT, 256, 0, stream>>>(x, Wq, Wk, Wv, P);
  k_jacobi_log<<<3 * kNMAT / 4, 256, 0, stream>>>(P, sq);
  k_attn<<<dim3(4, kBS), 256, 0, stream>>>(P, sq, attn);
  k_meanlog<<<dim3(4, kBS), 256, 0, stream>>>(attn, P, ML);
  k_expm<<<kNMAT / 4, 256, 0, stream>>>(ML, out);
}

// Round 5
// 501.692 us; speedup vs baseline: 2.1162x; 1.2004x over previous
//
#include <hip/hip_runtime.h>
#include <math.h>

// Problem constants
constexpr int kBS = 32, kM = 128, kNMAT = kBS * kM;         // 4096 (b,m) pairs
constexpr int kDIN = 64, kDOUT = 32, kMSZ = kDOUT * kDOUT;  // 1024 floats per 32x32
constexpr int kNSweep = 5;  // 6->5: absmax was sweep-insensitive at 6 (f32 floor)

// ws layout (floats):
//   P/log : [3][4096][1024]  (Q=0,K=1,V=2; overwritten in place by logs)
//   sumsq : [3][4096]        (||log||_F^2 per matrix)
//   attn  : [32][128][128]
// mean_log reuses the logQ region (dead after k_attn).
constexpr size_t OFF_SS   = (size_t)3 * kNMAT * kMSZ;
constexpr size_t OFF_ATTN = OFF_SS + (size_t)3 * kNMAT;

#define F4(p)  (*(float4*)(p))
#define CF4(p) (*(const float4*)(p))

// ---------------------------------------------------------------- bimap ----
// P_t = W_t^T X W_t for t in {Q,K,V}; one block per (b,m).
__global__ __launch_bounds__(256) void k_bimap(
    const float* __restrict__ x, const float* __restrict__ Wq,
    const float* __restrict__ Wk, const float* __restrict__ Wv,
    float* __restrict__ P) {
  __shared__ float Xs[64 * 68];   // X, row-major padded
  __shared__ float Wsh[64 * 32];  // current W, row-major
  __shared__ float Ts[64 * 36];   // T = X*W, padded
  const int t = threadIdx.x;
  const int bm = blockIdx.x;
  const float* xp = x + (size_t)bm * (kDIN * kDIN);
  {
    const int f0 = t * 16;
    const int r = f0 >> 6, c = f0 & 63;
    const float* src = xp + f0;
    float* dst = &Xs[r * 68 + c];
#pragma unroll
    for (int i = 0; i < 4; ++i) F4(dst + 4 * i) = CF4(src + 4 * i);
  }
  const int r0 = (t >> 3) * 2;   // stage-1 rows
  const int j0 = (t & 7) * 4;    // output cols
  const int i2 = t >> 3;         // stage-2 row
  for (int tt = 0; tt < 3; ++tt) {
    const float* W = (tt == 0) ? Wq : ((tt == 1) ? Wk : Wv);
    __syncthreads();  // protect Wsh/Ts from previous type (also covers Xs @ tt=0)
    F4(&Wsh[t * 8]) = CF4(W + t * 8);
    F4(&Wsh[t * 8 + 4]) = CF4(W + t * 8 + 4);
    __syncthreads();
    // stage 1: T = X * W   (64x32)
    float a0[4] = {0.f, 0.f, 0.f, 0.f}, a1[4] = {0.f, 0.f, 0.f, 0.f};
    for (int k = 0; k < 64; ++k) {
      const float x0 = Xs[r0 * 68 + k];
      const float x1 = Xs[(r0 + 1) * 68 + k];
      const float4 w = CF4(&Wsh[k * 32 + j0]);
      a0[0] += x0 * w.x; a0[1] += x0 * w.y; a0[2] += x0 * w.z; a0[3] += x0 * w.w;
      a1[0] += x1 * w.x; a1[1] += x1 * w.y; a1[2] += x1 * w.z; a1[3] += x1 * w.w;
    }
    F4(&Ts[r0 * 36 + j0])       = make_float4(a0[0], a0[1], a0[2], a0[3]);
    F4(&Ts[(r0 + 1) * 36 + j0]) = make_float4(a1[0], a1[1], a1[2], a1[3]);
    __syncthreads();
    // stage 2: P = W^T * T  (32x32)
    float b4[4] = {0.f, 0.f, 0.f, 0.f};
    for (int p = 0; p < 64; ++p) {
      const float wv = Wsh[p * 32 + i2];
      const float4 tv = CF4(&Ts[p * 36 + j0]);
      b4[0] += wv * tv.x; b4[1] += wv * tv.y; b4[2] += wv * tv.z; b4[3] += wv * tv.w;
    }
    F4(&P[((size_t)tt * kNMAT + bm) * kMSZ + i2 * 32 + j0]) =
        make_float4(b4[0], b4[1], b4[2], b4[3]);
  }
}

// ----------------------------------------------------- one-sided Jacobi ----
// Register-resident Brent-Luk one-sided Jacobi, TWO matrices per wave:
// matrix = lane>>5 (lanes 0-31 / 32-63), g=lane&15 (pair group),
// sub=(lane>>4)&1 (row half, 16 elems per lane per column).
// Per-wave scalar work (rotation transcendentals, norm update, shuffle)
// is issued once for 2 matrices -> halved per matrix vs 1-mat/wave.
// Ring exchange via update_dpp row_shl:1 / row_shr:1, bound_ctrl=off:
// out-of-range lanes keep `old`, which IS the tournament boundary value.
//   cpm = update_dpp(old=nq, src=np, row_shl:1) : g<=14 -> np[g+1], g15 -> nq
//   cp  = g==0 ? np : cpm
//   cq  = update_dpp(old=cpm, src=nq, row_shr:1): g>=1 -> nq[g-1], g0 -> np[1]
constexpr int kJSlot = 32 * 36 + 32;  // 1152 col data + 32 norms = 1184 floats
constexpr int kShl1 = 0x101, kShr1 = 0x111;

template <int CTRL>
__device__ __forceinline__ float updppf(float old_, float x) {
  return __builtin_bit_cast(float,
      __builtin_amdgcn_update_dpp(__builtin_bit_cast(int, old_),
                                  __builtin_bit_cast(int, x),
                                  CTRL, 0xf, 0xf, false));
}

__device__ __forceinline__ float xsign(float x, float s) {  // x * sgn(s)
  return __builtin_bit_cast(float,
      __builtin_bit_cast(int, x) ^
      (__builtin_bit_cast(int, s) & 0x80000000));
}

__global__ __launch_bounds__(256, 4) void k_jacobi_log(float* __restrict__ P,
                                                       float* __restrict__ sq) {
  __shared__ float lds[8 * kJSlot];  // 8 matrices per block
  const int t = threadIdx.x;
  const int wid = t >> 6, lane = t & 63;
  const int g = lane & 15;           // pair group
  const int sub = (lane >> 4) & 1;   // row half
  const int off = sub * 16;
  const size_t gid = (size_t)blockIdx.x * 8 + wid * 2 + (lane >> 5);
  float* A = P + gid * kMSZ;

  const bool is_g0 = (g == 0);
  // initial columns: g==0 -> {31, 0}; else {g, 31-g}
  const int p0 = is_g0 ? 31 : g;
  const int q0 = is_g0 ? 0 : 31 - g;

  float cp[16], cq[16];
  {  // A is symmetric: column c == row c (row-major, 32 floats)
    const float* pr = A + p0 * 32 + off;
    const float* qr = A + q0 * 32 + off;
#pragma unroll
    for (int i = 0; i < 16; i += 4) {
      const float4 a = CF4(pr + i);
      cp[i] = a.x; cp[i + 1] = a.y; cp[i + 2] = a.z; cp[i + 3] = a.w;
      const float4 b = CF4(qr + i);
      cq[i] = b.x; cq[i + 1] = b.y; cq[i + 2] = b.z; cq[i + 3] = b.w;
    }
  }
  // initial squared norms (reduce across the 2 subs: lanes l, l^16)
  float app = 0.f, aqq = 0.f;
#pragma unroll
  for (int i = 0; i < 16; ++i) {
    app = fmaf(cp[i], cp[i], app);
    aqq = fmaf(cq[i], cq[i], aqq);
  }
  app += __shfl_xor(app, 16);
  aqq += __shfl_xor(aqq, 16);

  for (int sw = 0; sw < kNSweep; ++sw) {
    for (int r = 0; r < 31; ++r) {
      // apq = colp . colq (two FMA chains for ILP, then cross-sub reduce)
      float d0 = cp[0] * cq[0], d1 = cp[1] * cq[1];
#pragma unroll
      for (int i = 2; i < 16; i += 2) {
        d0 = fmaf(cp[i], cq[i], d0);
        d1 = fmaf(cp[i + 1], cq[i + 1], d1);
      }
      float apq = d0 + d1;
      apq += __shfl_xor(apq, 16);
      // rotation from (d, apq) with 3 transcendentals:
      //   h = sqrt(d^2 + 4 apq^2); t = sgn(d) * 2 apq / (|d| + h)
      //   c = rsq(1+t^2); s = t*c.   apq==0 -> t=0 -> exact identity.
      const float d = aqq - app;
      const float apq2 = 2.f * apq;
      float h2 = fmaf(d, d, apq2 * apq2);
      h2 = fmaxf(h2, 1e-38f);  // guard d=apq=0
      const float hr = __builtin_amdgcn_rsqf(h2);
      const float h = h2 * hr;
      const float den = fabsf(d) + h;
      const float t0 = apq2 * __builtin_amdgcn_rcpf(den);
      const float tt = xsign(t0, d);
      const float c = __builtin_amdgcn_rsqf(fmaf(tt, tt, 1.f));
      const float sn = tt * c;
      float np[16], nq[16];
#pragma unroll
      for (int i = 0; i < 16; ++i) {
        const float t1 = c * cp[i];
        const float t2 = sn * cp[i];
        np[i] = fmaf(-sn, cq[i], t1);
        nq[i] = fmaf(c, cq[i], t2);
      }
      // analytic norm update (rotation preserves app+aqq; np.nq == 0)
      const float c2 = c * c, s2 = sn * sn, cs2 = 2.f * c * sn;
      const float capp = fmaf(c2, app, fmaf(s2, aqq, -cs2 * apq));
      const float caqq = (app + aqq) - capp;
      // ring exchange (see header comment)
#pragma unroll
      for (int i = 0; i < 16; ++i) {
        const float cpm = updppf<kShl1>(nq[i], np[i]);
        cp[i] = is_g0 ? np[i] : cpm;
        cq[i] = updppf<kShr1>(cpm, nq[i]);
      }
      {
        const float capm = updppf<kShl1>(caqq, capp);
        app = is_g0 ? capp : capm;
        aqq = updppf<kShr1>(capm, caqq);
      }
    }
  }
  // write final columns to this matrix's LDS slot (column-major, stride 36)
  {
    float* Bs = lds + (wid * 2 + (lane >> 5)) * kJSlot;
#pragma unroll
    for (int i = 0; i < 16; i += 4) {
      F4(&Bs[p0 * 36 + off + i]) = make_float4(cp[i], cp[i+1], cp[i+2], cp[i+3]);
      F4(&Bs[q0 * 36 + off + i]) = make_float4(cq[i], cq[i+1], cq[i+2], cq[i+3]);
    }
  }
  __builtin_amdgcn_wave_barrier();
  // two full-wave epilogue passes, one per matrix
  const size_t gbase = (size_t)blockIdx.x * 8 + wid * 2;
#pragma unroll
  for (int m = 0; m < 2; ++m) {
    float* Bs = lds + (wid * 2 + m) * kJSlot;
    float* ncol = Bs + 1152;
    const size_t gm = gbase + m;
    float* Am = P + gm * kMSZ;
    {  // exact column norms -> sigma^2; w_c = log(sigma)/sigma^2; sumsq
      const int cc_ = lane & 31, h = lane >> 5;
      const float* col = &Bs[cc_ * 36 + h * 16];
      float ssum = 0.f;
#pragma unroll
      for (int i = 0; i < 16; i += 4) {
        const float4 v = CF4(col + i);
        ssum += v.x * v.x + v.y * v.y + v.z * v.z + v.w * v.w;
      }
      ssum += __shfl_xor(ssum, 32);
      const float lg = 0.5f * logf(ssum);  // log sigma_c
      float tot = lg * lg;
      tot += __shfl_xor(tot, 1);  tot += __shfl_xor(tot, 2);
      tot += __shfl_xor(tot, 4);  tot += __shfl_xor(tot, 8);
      tot += __shfl_xor(tot, 16); tot += __shfl_xor(tot, 32);
      if (lane == 0) sq[gm] = 0.5f * tot;  // each column counted twice
      if (h == 0) ncol[cc_] = lg / ssum;
    }
    __builtin_amdgcn_wave_barrier();
    {  // log A = B diag(w) B^T, 4x4 tile per lane, write back (row-major)
      const int rr = (lane >> 3) * 4, cc = (lane & 7) * 4;
      float acc[4][4] = {};
      for (int c = 0; c < 32; ++c) {
        const float w = ncol[c];
        const float4 br = CF4(&Bs[c * 36 + rr]);
        const float4 bc = CF4(&Bs[c * 36 + cc]);
        const float wr[4]  = {w * br.x, w * br.y, w * br.z, w * br.w};
        const float bcv[4] = {bc.x, bc.y, bc.z, bc.w};
#pragma unroll
        for (int i = 0; i < 4; ++i)
#pragma unroll
          for (int j2 = 0; j2 < 4; ++j2) acc[i][j2] += wr[i] * bcv[j2];
      }
#pragma unroll
      for (int i = 0; i < 4; ++i)
        F4(&Am[(rr + i) * 32 + cc]) =
            make_float4(acc[i][0], acc[i][1], acc[i][2], acc[i][3]);
    }
    __builtin_amdgcn_wave_barrier();
  }
}

// ------------------------------------------------- scores/softmax/attn ----
// Block: (jt, b); computes scores[i=0..127][j in 32-wide tile], softmax over i,
// writes attn[b][j][i].
__global__ __launch_bounds__(256) void k_attn(
    const float* __restrict__ P, const float* __restrict__ sq,
    float* __restrict__ attn) {
  __shared__ float Ks[128 * 36];  // logK chunk, later reused for scores
  __shared__ float Qs[32 * 36];
  __shared__ float red[8 * 36];
  __shared__ float mcol[32];
  __shared__ float scol[32];
  const int t = threadIdx.x;
  const int b = blockIdx.y, jt = blockIdx.x;
  const int j0g = jt * 32;
  const float* logK = P + ((size_t)kNMAT + (size_t)b * kM) * kMSZ;
  const float* logQ = P + ((size_t)b * kM + j0g) * kMSZ;
  const int i0 = (t >> 3) * 4, j0 = (t & 7) * 4;
  float acc[4][4] = {};
  for (int dc = 0; dc < kMSZ; dc += 32) {
    __syncthreads();
    {  // stage logK rows 0..127, cols dc..dc+31
      const int r = t >> 1, c0 = (t & 1) * 16;
      const float* src = logK + (size_t)r * kMSZ + dc + c0;
      float* dst = &Ks[r * 36 + c0];
#pragma unroll
      for (int i = 0; i < 4; ++i) F4(dst + 4 * i) = CF4(src + 4 * i);
    }
    {  // stage logQ tile rows
      const int r = t >> 3, c0 = (t & 7) * 4;
      F4(&Qs[r * 36 + c0]) = CF4(logQ + (size_t)r * kMSZ + dc + c0);
    }
    __syncthreads();
    for (int k = 0; k < 32; ++k) {
      float kv[4], qv[4];
#pragma unroll
      for (int i = 0; i < 4; ++i) kv[i] = Ks[(i0 + i) * 36 + k];
#pragma unroll
      for (int j2 = 0; j2 < 4; ++j2) qv[j2] = Qs[(j0 + j2) * 36 + k];
#pragma unroll
      for (int i = 0; i < 4; ++i)
#pragma unroll
        for (int j2 = 0; j2 < 4; ++j2) acc[i][j2] += kv[i] * qv[j2];
    }
  }
  __syncthreads();
  {  // energy -> scores, into Ks[i][jl]
    float k2v[4], q2v[4];
#pragma unroll
    for (int i = 0; i < 4; ++i) k2v[i] = sq[kNMAT + b * kM + i0 + i];
#pragma unroll
    for (int j2 = 0; j2 < 4; ++j2) q2v[j2] = sq[b * kM + j0g + j0 + j2];
#pragma unroll
    for (int i = 0; i < 4; ++i)
#pragma unroll
      for (int j2 = 0; j2 < 4; ++j2) {
        float e = k2v[i] + q2v[j2] - 2.f * acc[i][j2];
        e = fmaxf(e, 0.f);
        Ks[(i0 + i) * 36 + (j0 + j2)] = 1.f / (1.f + log1pf(e));
      }
  }
  __syncthreads();
  const int jl = t & 31, grp = t >> 5;
  {
    float m = -1e30f;
    for (int i = grp * 16; i < grp * 16 + 16; ++i) m = fmaxf(m, Ks[i * 36 + jl]);
    red[grp * 36 + jl] = m;
  }
  __syncthreads();
  if (t < 32) {
    float m = red[t];
#pragma unroll
    for (int g = 1; g < 8; ++g) m = fmaxf(m, red[g * 36 + t]);
    mcol[t] = m;
  }
  __syncthreads();
  {
    const float mj = mcol[jl];
    float s = 0.f;
    for (int i = grp * 16; i < grp * 16 + 16; ++i) s += expf(Ks[i * 36 + jl] - mj);
    red[grp * 36 + jl] = s;
  }
  __syncthreads();
  if (t < 32) {
    float s = red[t];
#pragma unroll
    for (int g = 1; g < 8; ++g) s += red[g * 36 + t];
    scol[t] = 1.f / s;
  }
  __syncthreads();
  {  // write attn[b][j][i], coalesced in i
    const int il = t & 31, jg = t >> 5;
#pragma unroll
    for (int rep = 0; rep < 4; ++rep) {
      const int j2 = jg + rep * 8;
      const float mj = mcol[j2], is = scol[j2];
      float* dst = attn + ((size_t)b * kM + j0g + j2) * kM;
#pragma unroll
      for (int c4 = 0; c4 < 4; ++c4) {
        const int i = il + c4 * 32;
        dst[i] = expf(Ks[i * 36 + j2] - mj) * is;
      }
    }
  }
}

// -------------------------------------------------------------- meanlog ----
// ML[b][j][:] = sum_i attn[b][j][i] * logV[b][i][:]   (GEMM 32x1024, K=128)
__global__ __launch_bounds__(256) void k_meanlog(
    const float* __restrict__ attn, const float* __restrict__ P,
    float* __restrict__ ML) {
  __shared__ float As[32 * 132];
  __shared__ float Vs[128 * 64];
  const int t = threadIdx.x;
  const int b = blockIdx.y, jt = blockIdx.x;
  const int j0g = jt * 32;
  const float* logV = P + ((size_t)2 * kNMAT + (size_t)b * kM) * kMSZ;
  {  // stage attn tile [32][128]
    const int r = t >> 3, c0 = (t & 7) * 16;
    const float* src = attn + ((size_t)b * kM + j0g + r) * kM + c0;
    float* dst = &As[r * 132 + c0];
#pragma unroll
    for (int i = 0; i < 4; ++i) F4(dst + 4 * i) = CF4(src + 4 * i);
  }
  const int j0 = (t >> 4) * 2, d0 = (t & 15) * 4;
  for (int dc = 0; dc < kMSZ; dc += 64) {
    __syncthreads();
    {  // stage logV[k=0..127][dc..dc+63]
      const int r = t >> 1, c0 = (t & 1) * 32;
      const float* src = logV + (size_t)r * kMSZ + dc + c0;
      float* dst = &Vs[r * 64 + c0];
#pragma unroll
      for (int i = 0; i < 8; ++i) F4(dst + 4 * i) = CF4(src + 4 * i);
    }
    __syncthreads();
    float a0[4] = {0.f,0.f,0.f,0.f}, a1[4] = {0.f,0.f,0.f,0.f};
    for (int k = 0; k < kM; ++k) {
      const float w0 = As[(j0 + 0) * 132 + k];
      const float w1 = As[(j0 + 1) * 132 + k];
      const float4 v = CF4(&Vs[k * 64 + d0]);
      a0[0] += w0 * v.x; a0[1] += w0 * v.y; a0[2] += w0 * v.z; a0[3] += w0 * v.w;
      a1[0] += w1 * v.x; a1[1] += w1 * v.y; a1[2] += w1 * v.z; a1[3] += w1 * v.w;
    }
    F4(&ML[((size_t)b * kM + j0g + j0 + 0) * kMSZ + dc + d0]) =
        make_float4(a0[0], a0[1], a0[2], a0[3]);
    F4(&ML[((size_t)b * kM + j0g + j0 + 1) * kMSZ + dc + d0]) =
        make_float4(a1[0], a1[1], a1[2], a1[3]);
  }
}

// ------------------------------------------------------------------ exp ----
// out = exp(S): scaling-and-squaring + degree-10 Horner Taylor.
// 4 waves/block, one matrix per wave in a private LDS slot; no s_barrier.
// T updated IN PLACE: within one wave all ds_reads of an iteration precede
// its ds_writes in program order, and the DS unit is in-order per wave.
constexpr int kESlot = 2 * 1152;  // Mb + Tb

__global__ __launch_bounds__(256) void k_expm(const float* __restrict__ ML,
                                              float* __restrict__ out) {
  __shared__ float lds[4 * kESlot];
  const int t = threadIdx.x;
  const int wid = t >> 6, lane = t & 63;
  const size_t bm = (size_t)blockIdx.x * 4 + wid;
  float* Mb = lds + wid * kESlot;
  float* Tb = Mb + 1152;
  const float* S = ML + bm * kMSZ;
  const int r = lane >> 1, c0 = (lane & 1) * 16;
  float4 v0 = CF4(S + r * 32 + c0),     v1 = CF4(S + r * 32 + c0 + 4),
         v2 = CF4(S + r * 32 + c0 + 8), v3 = CF4(S + r * 32 + c0 + 12);
  float lsum = v0.x*v0.x + v0.y*v0.y + v0.z*v0.z + v0.w*v0.w
             + v1.x*v1.x + v1.y*v1.y + v1.z*v1.z + v1.w*v1.w
             + v2.x*v2.x + v2.y*v2.y + v2.z*v2.z + v2.w*v2.w
             + v3.x*v3.x + v3.y*v3.y + v3.z*v3.z + v3.w*v3.w;
#pragma unroll
  for (int d = 1; d < 64; d <<= 1) lsum += __shfl_xor(lsum, d);
  const float fn = sqrtf(lsum);     // Frobenius norm >= spectral norm
  int sc = 0;
  if (fn > 0.5f) sc = (int)ceilf(log2f(fn * 2.0f));
  const float scale = exp2f((float)(-sc));
  v0.x*=scale; v0.y*=scale; v0.z*=scale; v0.w*=scale;
  v1.x*=scale; v1.y*=scale; v1.z*=scale; v1.w*=scale;
  v2.x*=scale; v2.y*=scale; v2.z*=scale; v2.w*=scale;
  v3.x*=scale; v3.y*=scale; v3.z*=scale; v3.w*=scale;
  F4(&Mb[r * 36 + c0])      = v0;
  F4(&Mb[r * 36 + c0 + 4])  = v1;
  F4(&Mb[r * 36 + c0 + 8])  = v2;
  F4(&Mb[r * 36 + c0 + 12]) = v3;
  __builtin_amdgcn_wave_barrier();
  const int rr = (lane >> 3) * 4, cc = (lane & 7) * 4;
#pragma unroll
  for (int i = 0; i < 4; ++i) {  // T = I + M/10
    float4 v = F4(&Mb[(rr + i) * 36 + cc]);
    v.x = v.x * 0.1f + ((rr + i == cc + 0) ? 1.f : 0.f);
    v.y = v.y * 0.1f + ((rr + i == cc + 1) ? 1.f : 0.f);
    v.z = v.z * 0.1f + ((rr + i == cc + 2) ? 1.f : 0.f);
    v.w = v.w * 0.1f + ((rr + i == cc + 3) ? 1.f : 0.f);
    F4(&Tb[(rr + i) * 36 + cc]) = v;
  }
  __builtin_amdgcn_wave_barrier();
  for (int j = 9; j >= 1; --j) {  // T <- I + (M*T)/j, in place
    float a4[4][4] = {};
    for (int k = 0; k < 32; ++k) {
      float mv[4];
#pragma unroll
      for (int i = 0; i < 4; ++i) mv[i] = Mb[(rr + i) * 36 + k];
      const float4 tv = CF4(&Tb[k * 36 + cc]);
      const float tvv[4] = {tv.x, tv.y, tv.z, tv.w};
#pragma unroll
      for (int i = 0; i < 4; ++i)
#pragma unroll
        for (int j2 = 0; j2 < 4; ++j2) a4[i][j2] += mv[i] * tvv[j2];
    }
    const float inv = 1.f / (float)j;
#pragma unroll
    for (int i = 0; i < 4; ++i) {
      float4 v;
      v.x = a4[i][0] * inv + ((rr + i == cc + 0) ? 1.f : 0.f);
      v.y = a4[i][1] * inv + ((rr + i == cc + 1) ? 1.f : 0.f);
      v.z = a4[i][2] * inv + ((rr + i == cc + 2) ? 1.f : 0.f);
      v.w = a4[i][3] * inv + ((rr + i == cc + 3) ? 1.f : 0.f);
      F4(&Tb[(rr + i) * 36 + cc]) = v;
    }
    __builtin_amdgcn_wave_barrier();
  }
  for (int st = 0; st < sc; ++st) {  // T <- T*T, in place (wave-uniform trip count)
    float a4[4][4] = {};
    for (int k = 0; k < 32; ++k) {
      float mv[4];
#pragma unroll
      for (int i = 0; i < 4; ++i) mv[i] = Tb[(rr + i) * 36 + k];
      const float4 tv = CF4(&Tb[k * 36 + cc]);
      const float tvv[4] = {tv.x, tv.y, tv.z, tv.w};
#pragma unroll
      for (int i = 0; i < 4; ++i)
#pragma unroll
        for (int j2 = 0; j2 < 4; ++j2) a4[i][j2] += mv[i] * tvv[j2];
    }
#pragma unroll
    for (int i = 0; i < 4; ++i)
      F4(&Tb[(rr + i) * 36 + cc]) =
          make_float4(a4[i][0], a4[i][1], a4[i][2], a4[i][3]);
    __builtin_amdgcn_wave_barrier();
  }
#pragma unroll
  for (int i = 0; i < 4; ++i) {
    const float4 v = CF4(&Tb[(rr + i) * 36 + cc]);
    F4(&out[bm * kMSZ + (rr + i) * 32 + cc]) = v;
  }
}

// -------------------------------------------------------------- launch ----
extern "C" void kernel_launch(void* const* d_in, const int* in_sizes, int n_in,
                              void* d_out, int out_size, void* d_ws, size_t ws_size,
                              hipStream_t stream) {
  const float* x  = (const float*)d_in[0];
  const float* Wq = (const float*)d_in[1];
  const float* Wk = (const float*)d_in[2];
  const float* Wv = (const float*)d_in[3];
  float* ws   = (float*)d_ws;
  float* P    = ws;                 // [3][4096][1024]
  float* sq   = ws + OFF_SS;        // [3][4096]
  float* attn = ws + OFF_ATTN;      // [32][128][128]
  float* ML   = ws;                 // reuse logQ region (dead after k_attn)
  float* out  = (float*)d_out;

  k_bimap<<<kNMAT, 256, 0, stream>>>(x, Wq, Wk, Wv, P);
  k_jacobi_log<<<3 * kNMAT / 8, 256, 0, stream>>>(P, sq);
  k_attn<<<dim3(4, kBS), 256, 0, stream>>>(P, sq, attn);
  k_meanlog<<<dim3(4, kBS), 256, 0, stream>>>(attn, P, ML);
  k_expm<<<kNMAT / 4, 256, 0, stream>>>(ML, out);
}

// Round 6
// 420.432 us; speedup vs baseline: 2.5252x; 1.1933x over previous
//
#include <hip/hip_runtime.h>
#include <math.h>

// Problem constants
constexpr int kBS = 32, kM = 128, kNMAT = kBS * kM;         // 4096 (b,m) pairs
constexpr int kDIN = 64, kDOUT = 32, kMSZ = kDOUT * kDOUT;  // 1024 floats per 32x32
constexpr int kNSweep = 4;  // 8->6->5 all bit-identical absmax (bf16 floor); 4 still has margin

// ws layout (floats):
//   P/log : [3][4096][1024]  (Q=0,K=1,V=2; overwritten in place by logs)
//   sumsq : [3][4096]        (||log||_F^2 per matrix)
//   attn  : [32][128][128]
// mean_log reuses the logQ region (dead after k_attn).
constexpr size_t OFF_SS   = (size_t)3 * kNMAT * kMSZ;
constexpr size_t OFF_ATTN = OFF_SS + (size_t)3 * kNMAT;

#define F4(p)  (*(float4*)(p))
#define CF4(p) (*(const float4*)(p))

// ---------------------------------------------------------------- bimap ----
// P_t = W_t^T X W_t for t in {Q,K,V}; one block per (b,m).
__global__ __launch_bounds__(256) void k_bimap(
    const float* __restrict__ x, const float* __restrict__ Wq,
    const float* __restrict__ Wk, const float* __restrict__ Wv,
    float* __restrict__ P) {
  __shared__ float Xs[64 * 68];   // X, row-major padded
  __shared__ float Wsh[64 * 32];  // current W, row-major
  __shared__ float Ts[64 * 36];   // T = X*W, padded
  const int t = threadIdx.x;
  const int bm = blockIdx.x;
  const float* xp = x + (size_t)bm * (kDIN * kDIN);
  {
    const int f0 = t * 16;
    const int r = f0 >> 6, c = f0 & 63;
    const float* src = xp + f0;
    float* dst = &Xs[r * 68 + c];
#pragma unroll
    for (int i = 0; i < 4; ++i) F4(dst + 4 * i) = CF4(src + 4 * i);
  }
  const int r0 = (t >> 3) * 2;   // stage-1 rows
  const int j0 = (t & 7) * 4;    // output cols
  const int i2 = t >> 3;         // stage-2 row
  for (int tt = 0; tt < 3; ++tt) {
    const float* W = (tt == 0) ? Wq : ((tt == 1) ? Wk : Wv);
    __syncthreads();  // protect Wsh/Ts from previous type (also covers Xs @ tt=0)
    F4(&Wsh[t * 8]) = CF4(W + t * 8);
    F4(&Wsh[t * 8 + 4]) = CF4(W + t * 8 + 4);
    __syncthreads();
    // stage 1: T = X * W   (64x32). X symmetric: X[r0][k] = Xs[k][r0] -> b64.
    float a0[4] = {0.f, 0.f, 0.f, 0.f}, a1[4] = {0.f, 0.f, 0.f, 0.f};
    for (int k = 0; k < 64; ++k) {
      const float2 x01 = *(const float2*)&Xs[k * 68 + r0];
      const float4 w = CF4(&Wsh[k * 32 + j0]);
      a0[0] += x01.x * w.x; a0[1] += x01.x * w.y; a0[2] += x01.x * w.z; a0[3] += x01.x * w.w;
      a1[0] += x01.y * w.x; a1[1] += x01.y * w.y; a1[2] += x01.y * w.z; a1[3] += x01.y * w.w;
    }
    F4(&Ts[r0 * 36 + j0])       = make_float4(a0[0], a0[1], a0[2], a0[3]);
    F4(&Ts[(r0 + 1) * 36 + j0]) = make_float4(a1[0], a1[1], a1[2], a1[3]);
    __syncthreads();
    // stage 2: P = W^T * T  (32x32)
    float b4[4] = {0.f, 0.f, 0.f, 0.f};
    for (int p = 0; p < 64; ++p) {
      const float wv = Wsh[p * 32 + i2];
      const float4 tv = CF4(&Ts[p * 36 + j0]);
      b4[0] += wv * tv.x; b4[1] += wv * tv.y; b4[2] += wv * tv.z; b4[3] += wv * tv.w;
    }
    F4(&P[((size_t)tt * kNMAT + bm) * kMSZ + i2 * 32 + j0]) =
        make_float4(b4[0], b4[1], b4[2], b4[3]);
  }
}

// ----------------------------------------------------- one-sided Jacobi ----
// Register-resident Brent-Luk one-sided Jacobi, TWO matrices per wave:
// matrix = lane>>5, g=lane&15 (pair group), sub=(lane>>4)&1 (row half).
// Ring exchange via update_dpp row_shl:1 / row_shr:1, bound_ctrl=off:
// out-of-range lanes keep `old`, which IS the tournament boundary value.
constexpr int kJSlot = 32 * 36 + 32;  // 1152 col data + 32 norms = 1184 floats
constexpr int kShl1 = 0x101, kShr1 = 0x111;

template <int CTRL>
__device__ __forceinline__ float updppf(float old_, float x) {
  return __builtin_bit_cast(float,
      __builtin_amdgcn_update_dpp(__builtin_bit_cast(int, old_),
                                  __builtin_bit_cast(int, x),
                                  CTRL, 0xf, 0xf, false));
}

__device__ __forceinline__ float xsign(float x, float s) {  // x * sgn(s)
  return __builtin_bit_cast(float,
      __builtin_bit_cast(int, x) ^
      (__builtin_bit_cast(int, s) & 0x80000000));
}

__global__ __launch_bounds__(256, 4) void k_jacobi_log(float* __restrict__ P,
                                                       float* __restrict__ sq) {
  __shared__ float lds[8 * kJSlot];  // 8 matrices per block
  const int t = threadIdx.x;
  const int wid = t >> 6, lane = t & 63;
  const int g = lane & 15;           // pair group
  const int sub = (lane >> 4) & 1;   // row half
  const int off = sub * 16;
  const size_t gid = (size_t)blockIdx.x * 8 + wid * 2 + (lane >> 5);
  float* A = P + gid * kMSZ;

  const bool is_g0 = (g == 0);
  // initial columns: g==0 -> {31, 0}; else {g, 31-g}
  const int p0 = is_g0 ? 31 : g;
  const int q0 = is_g0 ? 0 : 31 - g;

  float cp[16], cq[16];
  {  // A is symmetric: column c == row c (row-major, 32 floats)
    const float* pr = A + p0 * 32 + off;
    const float* qr = A + q0 * 32 + off;
#pragma unroll
    for (int i = 0; i < 16; i += 4) {
      const float4 a = CF4(pr + i);
      cp[i] = a.x; cp[i + 1] = a.y; cp[i + 2] = a.z; cp[i + 3] = a.w;
      const float4 b = CF4(qr + i);
      cq[i] = b.x; cq[i + 1] = b.y; cq[i + 2] = b.z; cq[i + 3] = b.w;
    }
  }
  // initial squared norms (reduce across the 2 subs: lanes l, l^16)
  float app = 0.f, aqq = 0.f;
#pragma unroll
  for (int i = 0; i < 16; ++i) {
    app = fmaf(cp[i], cp[i], app);
    aqq = fmaf(cq[i], cq[i], aqq);
  }
  app += __shfl_xor(app, 16);
  aqq += __shfl_xor(aqq, 16);

  for (int sw = 0; sw < kNSweep; ++sw) {
    for (int r = 0; r < 31; ++r) {
      // apq = colp . colq (two FMA chains for ILP, then cross-sub reduce)
      float d0 = cp[0] * cq[0], d1 = cp[1] * cq[1];
#pragma unroll
      for (int i = 2; i < 16; i += 2) {
        d0 = fmaf(cp[i], cq[i], d0);
        d1 = fmaf(cp[i + 1], cq[i + 1], d1);
      }
      float apq = d0 + d1;
      apq += __shfl_xor(apq, 16);
      // rotation from (d, apq) with 3 transcendentals:
      //   h = sqrt(d^2 + 4 apq^2); t = sgn(d) * 2 apq / (|d| + h)
      //   c = rsq(1+t^2); s = t*c.   apq==0 -> t=0 -> exact identity.
      const float d = aqq - app;
      const float apq2 = 2.f * apq;
      float h2 = fmaf(d, d, apq2 * apq2);
      h2 = fmaxf(h2, 1e-38f);  // guard d=apq=0
      const float hr = __builtin_amdgcn_rsqf(h2);
      const float h = h2 * hr;
      const float den = fabsf(d) + h;
      const float t0 = apq2 * __builtin_amdgcn_rcpf(den);
      const float tt = xsign(t0, d);
      const float c = __builtin_amdgcn_rsqf(fmaf(tt, tt, 1.f));
      const float sn = tt * c;
      float np[16], nq[16];
#pragma unroll
      for (int i = 0; i < 16; ++i) {
        const float t1 = c * cp[i];
        const float t2 = sn * cp[i];
        np[i] = fmaf(-sn, cq[i], t1);
        nq[i] = fmaf(c, cq[i], t2);
      }
      // analytic norm update (rotation preserves app+aqq; np.nq == 0)
      const float c2 = c * c, s2 = sn * sn, cs2 = 2.f * c * sn;
      const float capp = fmaf(c2, app, fmaf(s2, aqq, -cs2 * apq));
      const float caqq = (app + aqq) - capp;
      // ring exchange
#pragma unroll
      for (int i = 0; i < 16; ++i) {
        const float cpm = updppf<kShl1>(nq[i], np[i]);
        cp[i] = is_g0 ? np[i] : cpm;
        cq[i] = updppf<kShr1>(cpm, nq[i]);
      }
      {
        const float capm = updppf<kShl1>(caqq, capp);
        app = is_g0 ? capp : capm;
        aqq = updppf<kShr1>(capm, caqq);
      }
    }
  }
  // write final columns to this matrix's LDS slot (column-major, stride 36)
  {
    float* Bs = lds + (wid * 2 + (lane >> 5)) * kJSlot;
#pragma unroll
    for (int i = 0; i < 16; i += 4) {
      F4(&Bs[p0 * 36 + off + i]) = make_float4(cp[i], cp[i+1], cp[i+2], cp[i+3]);
      F4(&Bs[q0 * 36 + off + i]) = make_float4(cq[i], cq[i+1], cq[i+2], cq[i+3]);
    }
  }
  __builtin_amdgcn_wave_barrier();
  // two full-wave epilogue passes, one per matrix
  const size_t gbase = (size_t)blockIdx.x * 8 + wid * 2;
#pragma unroll
  for (int m = 0; m < 2; ++m) {
    float* Bs = lds + (wid * 2 + m) * kJSlot;
    float* ncol = Bs + 1152;
    const size_t gm = gbase + m;
    float* Am = P + gm * kMSZ;
    {  // exact column norms -> sigma^2; w_c = log(sigma)/sigma^2; sumsq
      const int cc_ = lane & 31, h = lane >> 5;
      const float* col = &Bs[cc_ * 36 + h * 16];
      float ssum = 0.f;
#pragma unroll
      for (int i = 0; i < 16; i += 4) {
        const float4 v = CF4(col + i);
        ssum += v.x * v.x + v.y * v.y + v.z * v.z + v.w * v.w;
      }
      ssum += __shfl_xor(ssum, 32);
      const float lg = 0.5f * logf(ssum);  // log sigma_c
      float tot = lg * lg;
      tot += __shfl_xor(tot, 1);  tot += __shfl_xor(tot, 2);
      tot += __shfl_xor(tot, 4);  tot += __shfl_xor(tot, 8);
      tot += __shfl_xor(tot, 16); tot += __shfl_xor(tot, 32);
      if (lane == 0) sq[gm] = 0.5f * tot;  // each column counted twice
      if (h == 0) ncol[cc_] = lg / ssum;
    }
    __builtin_amdgcn_wave_barrier();
    {  // log A = B diag(w) B^T, 4x4 tile per lane, write back (row-major)
      const int rr = (lane >> 3) * 4, cc = (lane & 7) * 4;
      float acc[4][4] = {};
      for (int c = 0; c < 32; ++c) {
        const float w = ncol[c];
        const float4 br = CF4(&Bs[c * 36 + rr]);
        const float4 bc = CF4(&Bs[c * 36 + cc]);
        const float wr[4]  = {w * br.x, w * br.y, w * br.z, w * br.w};
        const float bcv[4] = {bc.x, bc.y, bc.z, bc.w};
#pragma unroll
        for (int i = 0; i < 4; ++i)
#pragma unroll
          for (int j2 = 0; j2 < 4; ++j2) acc[i][j2] += wr[i] * bcv[j2];
      }
#pragma unroll
      for (int i = 0; i < 4; ++i)
        F4(&Am[(rr + i) * 32 + cc]) =
            make_float4(acc[i][0], acc[i][1], acc[i][2], acc[i][3]);
    }
    __builtin_amdgcn_wave_barrier();
  }
}

// ------------------------------------------------- scores/softmax/attn ----
// Block: (jt, b), 16-wide j tile -> 256 blocks (1/CU). K-chunk staged
// TRANSPOSED [k][i] so i-fragments are ds_read_b128; Q [k][j] -> b64.
__global__ __launch_bounds__(256) void k_attn(
    const float* __restrict__ P, const float* __restrict__ sq,
    float* __restrict__ attn) {
  __shared__ float Kt[32 * 132];   // [k][i], padded
  __shared__ float Qt[32 * 20];    // [k][j], padded
  __shared__ float Ss[128 * 20];   // scores [i][j]
  __shared__ float red[16 * 20];
  __shared__ float mcol[16];
  __shared__ float scol[16];
  const int t = threadIdx.x;
  const int b = blockIdx.y, jt = blockIdx.x;
  const int j0g = jt * 16;
  const float* logK = P + ((size_t)kNMAT + (size_t)b * kM) * kMSZ;
  const float* logQ = P + ((size_t)b * kM + j0g) * kMSZ;
  const int i0 = (t >> 3) * 4, j0 = (t & 7) * 2;
  float acc[4][2] = {};
  for (int dc = 0; dc < kMSZ; dc += 32) {
    __syncthreads();
    {  // stage Kt[k][i]: row r of logK, cols dc+c0..+15, transposed write
      const int r = t >> 1, c0 = (t & 1) * 16;
      const float* src = logK + (size_t)r * kMSZ + dc + c0;
#pragma unroll
      for (int ii = 0; ii < 16; ii += 4) {
        const float4 v = CF4(src + ii);
        Kt[(c0 + ii + 0) * 132 + r] = v.x;
        Kt[(c0 + ii + 1) * 132 + r] = v.y;
        Kt[(c0 + ii + 2) * 132 + r] = v.z;
        Kt[(c0 + ii + 3) * 132 + r] = v.w;
      }
    }
    {  // stage Qt[k][j]
      const int j = t >> 4, c0 = (t & 15) * 2;
      const float2 v = *(const float2*)(logQ + (size_t)j * kMSZ + dc + c0);
      Qt[(c0 + 0) * 20 + j] = v.x;
      Qt[(c0 + 1) * 20 + j] = v.y;
    }
    __syncthreads();
    for (int k = 0; k < 32; ++k) {
      const float4 kv = CF4(&Kt[k * 132 + i0]);
      const float2 qv = *(const float2*)&Qt[k * 20 + j0];
      acc[0][0] = fmaf(kv.x, qv.x, acc[0][0]);
      acc[0][1] = fmaf(kv.x, qv.y, acc[0][1]);
      acc[1][0] = fmaf(kv.y, qv.x, acc[1][0]);
      acc[1][1] = fmaf(kv.y, qv.y, acc[1][1]);
      acc[2][0] = fmaf(kv.z, qv.x, acc[2][0]);
      acc[2][1] = fmaf(kv.z, qv.y, acc[2][1]);
      acc[3][0] = fmaf(kv.w, qv.x, acc[3][0]);
      acc[3][1] = fmaf(kv.w, qv.y, acc[3][1]);
    }
  }
  {  // energy -> scores, into Ss[i][j]
    float k2v[4], q2v[2];
#pragma unroll
    for (int i = 0; i < 4; ++i) k2v[i] = sq[kNMAT + b * kM + i0 + i];
#pragma unroll
    for (int j2 = 0; j2 < 2; ++j2) q2v[j2] = sq[b * kM + j0g + j0 + j2];
#pragma unroll
    for (int i = 0; i < 4; ++i)
#pragma unroll
      for (int j2 = 0; j2 < 2; ++j2) {
        float e = k2v[i] + q2v[j2] - 2.f * acc[i][j2];
        e = fmaxf(e, 0.f);
        Ss[(i0 + i) * 20 + (j0 + j2)] = 1.f / (1.f + log1pf(e));
      }
  }
  __syncthreads();
  const int jl = t & 15, grp = t >> 4;  // 16 groups x 16 j-cols; group: 8 i-rows
  {
    float m = -1e30f;
#pragma unroll
    for (int i = 0; i < 8; ++i) m = fmaxf(m, Ss[(grp * 8 + i) * 20 + jl]);
    red[grp * 20 + jl] = m;
  }
  __syncthreads();
  if (t < 16) {
    float m = red[t];
#pragma unroll
    for (int g = 1; g < 16; ++g) m = fmaxf(m, red[g * 20 + t]);
    mcol[t] = m;
  }
  __syncthreads();
  {
    const float mj = mcol[jl];
    float s = 0.f;
#pragma unroll
    for (int i = 0; i < 8; ++i) s += expf(Ss[(grp * 8 + i) * 20 + jl] - mj);
    red[grp * 20 + jl] = s;
  }
  __syncthreads();
  if (t < 16) {
    float s = red[t];
#pragma unroll
    for (int g = 1; g < 16; ++g) s += red[g * 20 + t];
    scol[t] = 1.f / s;
  }
  __syncthreads();
  {  // write attn[b][j][i], coalesced in i
    const int il = t & 31, jg = t >> 5;
#pragma unroll
    for (int rep = 0; rep < 2; ++rep) {
      const int j2 = jg + rep * 8;
      const float mj = mcol[j2], is = scol[j2];
      float* dst = attn + ((size_t)b * kM + j0g + j2) * kM;
#pragma unroll
      for (int c4 = 0; c4 < 4; ++c4) {
        const int i = il + c4 * 32;
        dst[i] = expf(Ss[i * 20 + j2] - mj) * is;
      }
    }
  }
}

// -------------------------------------------------------------- meanlog ----
// ML[b][j][:] = sum_i attn[b][j][i] * logV[b][i][:]. Block: (jt, b), 16 j.
// All 16 j-accumulators in registers (thread owns 4 d-cols); attn weights
// broadcast from LDS (b128 per 4k); V streamed from global (L2-resident).
__global__ __launch_bounds__(256) void k_meanlog(
    const float* __restrict__ attn, const float* __restrict__ P,
    float* __restrict__ ML) {
  __shared__ float As[16 * 132];
  const int t = threadIdx.x;
  const int b = blockIdx.y, jt = blockIdx.x;
  const int j0g = jt * 16;
  const float* logV = P + ((size_t)2 * kNMAT + (size_t)b * kM) * kMSZ;
  {  // stage attn tile [16][128]
    const int j = t >> 4, k0 = (t & 15) * 8;
    const float* src = attn + ((size_t)b * kM + j0g + j) * kM + k0;
    F4(&As[j * 132 + k0])     = CF4(src);
    F4(&As[j * 132 + k0 + 4]) = CF4(src + 4);
  }
  __syncthreads();
  const int d0 = t * 4;
  float acc[16][4] = {};
  for (int k = 0; k < kM; k += 4) {
    float4 vr[4];
#pragma unroll
    for (int kk = 0; kk < 4; ++kk)
      vr[kk] = CF4(&logV[(size_t)(k + kk) * kMSZ + d0]);
#pragma unroll
    for (int j = 0; j < 16; ++j) {
      const float4 w = CF4(&As[j * 132 + k]);
      const float wv[4] = {w.x, w.y, w.z, w.w};
#pragma unroll
      for (int kk = 0; kk < 4; ++kk) {
        const float* vv = (const float*)&vr[kk];
#pragma unroll
        for (int dd = 0; dd < 4; ++dd)
          acc[j][dd] = fmaf(wv[kk], vv[dd], acc[j][dd]);
      }
    }
  }
#pragma unroll
  for (int j = 0; j < 16; ++j)
    F4(&ML[((size_t)b * kM + j0g + j) * kMSZ + d0]) =
        make_float4(acc[j][0], acc[j][1], acc[j][2], acc[j][3]);
}

// ------------------------------------------------------------------ exp ----
// out = exp(S): scaling-and-squaring + degree-10 Horner Taylor.
// 4 waves/block, one matrix per wave, private LDS slot, no s_barrier.
// M and T are SYMMETRIC, so row-fragments load as b128 from [k][r].
constexpr int kESlot = 2 * 1152;  // Mb + Tb

__global__ __launch_bounds__(256) void k_expm(const float* __restrict__ ML,
                                              float* __restrict__ out) {
  __shared__ float lds[4 * kESlot];
  const int t = threadIdx.x;
  const int wid = t >> 6, lane = t & 63;
  const size_t bm = (size_t)blockIdx.x * 4 + wid;
  float* Mb = lds + wid * kESlot;
  float* Tb = Mb + 1152;
  const float* S = ML + bm * kMSZ;
  const int r = lane >> 1, c0 = (lane & 1) * 16;
  float4 v0 = CF4(S + r * 32 + c0),     v1 = CF4(S + r * 32 + c0 + 4),
         v2 = CF4(S + r * 32 + c0 + 8), v3 = CF4(S + r * 32 + c0 + 12);
  float lsum = v0.x*v0.x + v0.y*v0.y + v0.z*v0.z + v0.w*v0.w
             + v1.x*v1.x + v1.y*v1.y + v1.z*v1.z + v1.w*v1.w
             + v2.x*v2.x + v2.y*v2.y + v2.z*v2.z + v2.w*v2.w
             + v3.x*v3.x + v3.y*v3.y + v3.z*v3.z + v3.w*v3.w;
#pragma unroll
  for (int d = 1; d < 64; d <<= 1) lsum += __shfl_xor(lsum, d);
  const float fn = sqrtf(lsum);     // Frobenius norm >= spectral norm
  int sc = 0;
  if (fn > 0.5f) sc = (int)ceilf(log2f(fn * 2.0f));
  const float scale = exp2f((float)(-sc));
  v0.x*=scale; v0.y*=scale; v0.z*=scale; v0.w*=scale;
  v1.x*=scale; v1.y*=scale; v1.z*=scale; v1.w*=scale;
  v2.x*=scale; v2.y*=scale; v2.z*=scale; v2.w*=scale;
  v3.x*=scale; v3.y*=scale; v3.z*=scale; v3.w*=scale;
  F4(&Mb[r * 36 + c0])      = v0;
  F4(&Mb[r * 36 + c0 + 4])  = v1;
  F4(&Mb[r * 36 + c0 + 8])  = v2;
  F4(&Mb[r * 36 + c0 + 12]) = v3;
  __builtin_amdgcn_wave_barrier();
  const int rr = (lane >> 3) * 4, cc = (lane & 7) * 4;
#pragma unroll
  for (int i = 0; i < 4; ++i) {  // T = I + M/10
    float4 v = F4(&Mb[(rr + i) * 36 + cc]);
    v.x = v.x * 0.1f + ((rr + i == cc + 0) ? 1.f : 0.f);
    v.y = v.y * 0.1f + ((rr + i == cc + 1) ? 1.f : 0.f);
    v.z = v.z * 0.1f + ((rr + i == cc + 2) ? 1.f : 0.f);
    v.w = v.w * 0.1f + ((rr + i == cc + 3) ? 1.f : 0.f);
    F4(&Tb[(rr + i) * 36 + cc]) = v;
  }
  __builtin_amdgcn_wave_barrier();
  for (int j = 9; j >= 1; --j) {  // T <- I + (M*T)/j, in place
    float a4[4][4] = {};
    for (int k = 0; k < 32; ++k) {
      const float4 mv = CF4(&Mb[k * 36 + rr]);  // M[rr..rr+3][k] by symmetry
      const float mvv[4] = {mv.x, mv.y, mv.z, mv.w};
      const float4 tv = CF4(&Tb[k * 36 + cc]);
      const float tvv[4] = {tv.x, tv.y, tv.z, tv.w};
#pragma unroll
      for (int i = 0; i < 4; ++i)
#pragma unroll
        for (int j2 = 0; j2 < 4; ++j2) a4[i][j2] += mvv[i] * tvv[j2];
    }
    const float inv = 1.f / (float)j;
#pragma unroll
    for (int i = 0; i < 4; ++i) {
      float4 v;
      v.x = a4[i][0] * inv + ((rr + i == cc + 0) ? 1.f : 0.f);
      v.y = a4[i][1] * inv + ((rr + i == cc + 1) ? 1.f : 0.f);
      v.z = a4[i][2] * inv + ((rr + i == cc + 2) ? 1.f : 0.f);
      v.w = a4[i][3] * inv + ((rr + i == cc + 3) ? 1.f : 0.f);
      F4(&Tb[(rr + i) * 36 + cc]) = v;
    }
    __builtin_amdgcn_wave_barrier();
  }
  for (int st = 0; st < sc; ++st) {  // T <- T*T, in place (T symmetric)
    float a4[4][4] = {};
    for (int k = 0; k < 32; ++k) {
      const float4 mv = CF4(&Tb[k * 36 + rr]);  // T[rr..rr+3][k] by symmetry
      const float mvv[4] = {mv.x, mv.y, mv.z, mv.w};
      const float4 tv = CF4(&Tb[k * 36 + cc]);
      const float tvv[4] = {tv.x, tv.y, tv.z, tv.w};
#pragma unroll
      for (int i = 0; i < 4; ++i)
#pragma unroll
        for (int j2 = 0; j2 < 4; ++j2) a4[i][j2] += mvv[i] * tvv[j2];
    }
#pragma unroll
    for (int i = 0; i < 4; ++i)
      F4(&Tb[(rr + i) * 36 + cc]) =
          make_float4(a4[i][0], a4[i][1], a4[i][2], a4[i][3]);
    __builtin_amdgcn_wave_barrier();
  }
#pragma unroll
  for (int i = 0; i < 4; ++i) {
    const float4 v = CF4(&Tb[(rr + i) * 36 + cc]);
    F4(&out[bm * kMSZ + (rr + i) * 32 + cc]) = v;
  }
}

// -------------------------------------------------------------- launch ----
extern "C" void kernel_launch(void* const* d_in, const int* in_sizes, int n_in,
                              void* d_out, int out_size, void* d_ws, size_t ws_size,
                              hipStream_t stream) {
  const float* x  = (const float*)d_in[0];
  const float* Wq = (const float*)d_in[1];
  const float* Wk = (const float*)d_in[2];
  const float* Wv = (const float*)d_in[3];
  float* ws   = (float*)d_ws;
  float* P    = ws;                 // [3][4096][1024]
  float* sq   = ws + OFF_SS;        // [3][4096]
  float* attn = ws + OFF_ATTN;      // [32][128][128]
  float* ML   = ws;                 // reuse logQ region (dead after k_attn)
  float* out  = (float*)d_out;

  k_bimap<<<kNMAT, 256, 0, stream>>>(x, Wq, Wk, Wv, P);
  k_jacobi_log<<<3 * kNMAT / 8, 256, 0, stream>>>(P, sq);
  k_attn<<<dim3(8, kBS), 256, 0, stream>>>(P, sq, attn);
  k_meanlog<<<dim3(8, kBS), 256, 0, stream>>>(attn, P, ML);
  k_expm<<<kNMAT / 4, 256, 0, stream>>>(ML, out);
}